// Round 1
// baseline (324.300 us; speedup 1.0000x reference)
//
#include <hip/hip_runtime.h>
#include <hip/hip_bf16.h>
#include <math.h>

// Problem constants
#define H_HEADS 8
#define DM 256       // d_model
#define PN 128       // patch_num
#define DK 32        // d_k
#define BATCH 32
#define ROWS 4096    // BATCH*PN

__device__ __forceinline__ float gelu_f(float x) {
    // jax.nn.gelu default approximate=True (tanh form)
    float inner = 0.7978845608028654f * (x + 0.044715f * x * x * x);
    return 0.5f * x * (1.0f + tanhf(inner));
}

// ---------------------------------------------------------------------------
// Kernel 1: A[h,n,:] = feats[h,n,:] @ fc_out_w[0:256,:]
//           B[h,n,:] = feats[h,n,:] @ fc_out_w[256:512,:]
// feats[h,n,d] = memory_w[n*2048 + h*256 + d]
// grid: 128 blocks = (h, ntile of 8), 256 threads (output col)
// ---------------------------------------------------------------------------
__global__ __launch_bounds__(256) void k_featproj(
    const float* __restrict__ memory_w, const float* __restrict__ fc_out_w,
    float* __restrict__ A, float* __restrict__ Bm) {
    int blk = blockIdx.x;
    int h = blk >> 4, n0 = (blk & 15) * 8;
    int t = threadIdx.x;
    __shared__ float f[8 * 256];
    #pragma unroll
    for (int ii = 0; ii < 8; ++ii) {
        int fi = t + ii * 256;
        int r = fi >> 8, d = fi & 255;
        f[fi] = memory_w[(n0 + r) * 2048 + h * 256 + d];
    }
    __syncthreads();
    float a[8] = {}, b[8] = {};
    #pragma unroll 4
    for (int d = 0; d < 256; ++d) {
        float wt = fc_out_w[d * 256 + t];
        float wb = fc_out_w[(d + 256) * 256 + t];
        #pragma unroll
        for (int r = 0; r < 8; ++r) {
            a[r] += f[r * 256 + d] * wt;
            b[r] += f[r * 256 + d] * wb;
        }
    }
    #pragma unroll
    for (int r = 0; r < 8; ++r) {
        A[(h * 128 + n0 + r) * 256 + t] = a[r];
        Bm[(h * 128 + n0 + r) * 256 + t] = b[r];
    }
}

// ---------------------------------------------------------------------------
// Kernel 2: conn[h,i,j] = 1 if (l1+g1) > (l0+g0) else 0
//   l_k = sum_d relu(A[h,j,d] + B[h,i,d] + fc_out_b[d]) * fc_cat_w[d,k] + fc_cat_b[k]
//   g_k = -log(-log(u_k + eps) + eps)
// grid: 256 blocks = (h, itile of 4), 128 threads (j)
// ---------------------------------------------------------------------------
__global__ __launch_bounds__(128) void k_conn(
    const float* __restrict__ A, const float* __restrict__ Bm,
    const float* __restrict__ fc_out_b, const float* __restrict__ fc_cat_w,
    const float* __restrict__ fc_cat_b, const float* __restrict__ gumbel_u,
    float* __restrict__ conn) {
    int blk = blockIdx.x;
    int h = blk >> 5, i0 = (blk & 31) * 4;
    int j = threadIdx.x;
    __shared__ float sB[4 * 256];
    __shared__ float sw0[256], sw1[256];
    for (int t = j; t < 256; t += 128) {
        float fb = fc_out_b[t];
        #pragma unroll
        for (int i = 0; i < 4; ++i)
            sB[i * 256 + t] = Bm[(h * 128 + i0 + i) * 256 + t] + fb;
        sw0[t] = fc_cat_w[t * 2];
        sw1[t] = fc_cat_w[t * 2 + 1];
    }
    __syncthreads();
    const float4* Arow4 = (const float4*)(A + (h * 128 + j) * 256);
    float cb0 = fc_cat_b[0], cb1 = fc_cat_b[1];
    float l0[4], l1[4];
    #pragma unroll
    for (int i = 0; i < 4; ++i) { l0[i] = cb0; l1[i] = cb1; }
    for (int d4 = 0; d4 < 64; ++d4) {
        float4 av = Arow4[d4];
        int d = d4 * 4;
        #pragma unroll
        for (int i = 0; i < 4; ++i) {
            float h0 = fmaxf(av.x + sB[i * 256 + d + 0], 0.f);
            float h1 = fmaxf(av.y + sB[i * 256 + d + 1], 0.f);
            float h2 = fmaxf(av.z + sB[i * 256 + d + 2], 0.f);
            float h3 = fmaxf(av.w + sB[i * 256 + d + 3], 0.f);
            l0[i] += h0 * sw0[d] + h1 * sw0[d + 1] + h2 * sw0[d + 2] + h3 * sw0[d + 3];
            l1[i] += h0 * sw1[d] + h1 * sw1[d + 1] + h2 * sw1[d + 2] + h3 * sw1[d + 3];
        }
    }
    #pragma unroll
    for (int i = 0; i < 4; ++i) {
        int gb = ((h * 128 + i0 + i) * 128 + j) * 2;
        float u0 = gumbel_u[gb], u1 = gumbel_u[gb + 1];
        float g0 = -logf(-logf(u0 + 1e-10f) + 1e-10f);
        float g1 = -logf(-logf(u1 + 1e-10f) + 1e-10f);
        conn[(h * 128 + i0 + i) * 128 + j] = ((l1[i] + g1) > (l0[i] + g0)) ? 1.f : 0.f;
    }
}

// ---------------------------------------------------------------------------
// Kernel 3 (generic): Y[M,256] = act(X[M,256] @ W[256,256] + bias)
// ACT: 0 = none, 1 = gelu
// grid: 256 blocks of 16 rows; 256 threads = 64 col-groups x 4 row-groups;
// each thread computes a 4x4 micro-tile.
// ---------------------------------------------------------------------------
template <int ACT>
__global__ __launch_bounds__(256) void k_rowgemm(
    const float* __restrict__ X, const float* __restrict__ W,
    const float* __restrict__ bias, float* __restrict__ Y) {
    __shared__ float xs[16 * 256];
    int t = threadIdx.x;
    int r0 = blockIdx.x * 16;
    #pragma unroll
    for (int ii = 0; ii < 4; ++ii) {
        int fi = t + ii * 256;
        int row = fi >> 6, c4 = (fi & 63) * 4;
        *(float4*)(xs + row * 256 + c4) = *(const float4*)(X + (r0 + row) * 256 + c4);
    }
    __syncthreads();
    int tc = (t & 63) * 4;
    int tr = (t >> 6) * 4;
    float acc[4][4] = {};
    const float* Wp = W + tc;
    #pragma unroll 8
    for (int k = 0; k < 256; ++k) {
        float4 w = *(const float4*)(Wp + k * 256);
        #pragma unroll
        for (int r = 0; r < 4; ++r) {
            float xv = xs[(tr + r) * 256 + k];
            acc[r][0] += xv * w.x;
            acc[r][1] += xv * w.y;
            acc[r][2] += xv * w.z;
            acc[r][3] += xv * w.w;
        }
    }
    float4 bv = *(const float4*)(bias + tc);
    #pragma unroll
    for (int r = 0; r < 4; ++r) {
        float o0 = acc[r][0] + bv.x, o1 = acc[r][1] + bv.y;
        float o2 = acc[r][2] + bv.z, o3 = acc[r][3] + bv.w;
        if (ACT == 1) { o0 = gelu_f(o0); o1 = gelu_f(o1); o2 = gelu_f(o2); o3 = gelu_f(o3); }
        float4 o = {o0, o1, o2, o3};
        *(float4*)(Y + (r0 + tr + r) * 256 + tc) = o;
    }
}

// ---------------------------------------------------------------------------
// Kernel 4: masked attention per (b,h).
// scores = q@k^T * scale + (conn-1)*1e9 ; softmax ; out = attn@v
// Layouts in global: Q/K/V/AO are [B, N, H*DK] (row = b*128+n, col = h*32+d).
// grid: 256 blocks = (b,h), 256 threads = 4 waves; each wave owns rows r = wv+4t.
// ---------------------------------------------------------------------------
__global__ __launch_bounds__(256) void k_attn(
    const float* __restrict__ Q, const float* __restrict__ K,
    const float* __restrict__ V, const float* __restrict__ conn,
    float* __restrict__ AO) {
    int bh = blockIdx.x;
    int b = bh >> 3, h = bh & 7;
    int t = threadIdx.x;
    int lane = t & 63, wv = t >> 6;
    __shared__ float qs[128 * 32];
    __shared__ float kT[32 * 129];  // transposed + padded (bank-conflict free)
    __shared__ float vs[128 * 32];
    __shared__ float ps[4][128];
    for (int idx = t; idx < 4096; idx += 256) {
        int r = idx >> 5, d = idx & 31;
        int g = b * 32768 + r * 256 + h * 32 + d;
        qs[idx] = Q[g];
        vs[idx] = V[g];
        kT[d * 129 + r] = K[g];
    }
    __syncthreads();
    const float scale = 0.17677669529663687f;  // 32^-0.5
    for (int r = wv; r < 128; r += 4) {
        int j1 = lane, j2 = lane + 64;
        float s1 = 0.f, s2 = 0.f;
        #pragma unroll
        for (int d = 0; d < 32; ++d) {
            float qv = qs[r * 32 + d];
            s1 += qv * kT[d * 129 + j1];
            s2 += qv * kT[d * 129 + j2];
        }
        const float* cr = conn + h * 16384 + r * 128;
        s1 = s1 * scale + (cr[j1] - 1.f) * 1e9f;
        s2 = s2 * scale + (cr[j2] - 1.f) * 1e9f;
        float m = fmaxf(s1, s2);
        #pragma unroll
        for (int off = 32; off > 0; off >>= 1) m = fmaxf(m, __shfl_xor(m, off));
        float e1 = expf(s1 - m), e2 = expf(s2 - m);
        float sm = e1 + e2;
        #pragma unroll
        for (int off = 32; off > 0; off >>= 1) sm += __shfl_xor(sm, off);
        ps[wv][j1] = e1;
        ps[wv][j2] = e2;
        float inv = 1.f / sm;
        int d = lane & 31, jq = lane >> 5;
        float acc = 0.f;
        #pragma unroll 8
        for (int jj = 0; jj < 64; ++jj) {
            int j = jq * 64 + jj;
            acc += ps[wv][j] * vs[j * 32 + d];
        }
        acc += __shfl_xor(acc, 32);
        if (lane < 32) AO[b * 32768 + r * 256 + h * 32 + d] = acc * inv;
    }
}

// ---------------------------------------------------------------------------
extern "C" void kernel_launch(void* const* d_in, const int* in_sizes, int n_in,
                              void* d_out, int out_size, void* d_ws, size_t ws_size,
                              hipStream_t stream) {
    const float* x        = (const float*)d_in[0];
    const float* gumbel_u = (const float*)d_in[1];
    const float* memory_w = (const float*)d_in[2];
    const float* fc_out_w = (const float*)d_in[3];
    const float* fc_out_b = (const float*)d_in[4];
    const float* fc_cat_w = (const float*)d_in[5];
    const float* fc_cat_b = (const float*)d_in[6];
    const float* wq       = (const float*)d_in[7];
    const float* bq       = (const float*)d_in[8];
    const float* wk       = (const float*)d_in[9];
    const float* bk       = (const float*)d_in[10];
    const float* wv_      = (const float*)d_in[11];
    const float* bv_      = (const float*)d_in[12];
    const float* out_w    = (const float*)d_in[13];
    const float* out_b    = (const float*)d_in[14];
    const float* mlp_w1   = (const float*)d_in[15];
    const float* mlp_b1   = (const float*)d_in[16];
    const float* mlp_w2   = (const float*)d_in[17];
    const float* mlp_b2   = (const float*)d_in[18];

    float* ws   = (float*)d_ws;
    float* A    = ws;                 //  262144 floats
    float* Bm   = ws + 262144;        //  262144
    float* conn = ws + 524288;        //  131072
    float* hbuf = ws + 655360;        // 1048576 (mlp hidden, later reused as attn out)
    float* xm   = ws + 1703936;       // 1048576
    float* q    = ws + 2752512;       // 1048576
    float* k    = ws + 3801088;       // 1048576
    float* v    = ws + 4849664;       // 1048576
    float* ao   = hbuf;               // reuse: hidden is dead after mlp2
    float* out  = (float*)d_out;

    k_featproj<<<dim3(128), dim3(256), 0, stream>>>(memory_w, fc_out_w, A, Bm);
    k_conn<<<dim3(256), dim3(128), 0, stream>>>(A, Bm, fc_out_b, fc_cat_w, fc_cat_b,
                                                gumbel_u, conn);
    k_rowgemm<1><<<dim3(256), dim3(256), 0, stream>>>(x, mlp_w1, mlp_b1, hbuf);
    k_rowgemm<0><<<dim3(256), dim3(256), 0, stream>>>(hbuf, mlp_w2, mlp_b2, xm);
    k_rowgemm<0><<<dim3(256), dim3(256), 0, stream>>>(xm, wq, bq, q);
    k_rowgemm<0><<<dim3(256), dim3(256), 0, stream>>>(xm, wk, bk, k);
    k_rowgemm<0><<<dim3(256), dim3(256), 0, stream>>>(xm, wv_, bv_, v);
    k_attn<<<dim3(256), dim3(256), 0, stream>>>(q, k, v, conn, ao);
    k_rowgemm<0><<<dim3(256), dim3(256), 0, stream>>>(ao, out_w, out_b, out);
}

// Round 2
// 311.766 us; speedup vs baseline: 1.0402x; 1.0402x over previous
//
#include <hip/hip_runtime.h>
#include <hip/hip_bf16.h>
#include <math.h>

// Problem constants: H=8, d_model=256, N=128, d_k=32, B=32, rows=4096

__device__ __forceinline__ float gelu_f(float x) {
    float inner = 0.7978845608028654f * (x + 0.044715f * x * x * x);
    return 0.5f * x * (1.0f + tanhf(inner));
}

// ---------------------------------------------------------------------------
// Kernel 1: A[h,n,:] = feats[h,n,:] @ fc_out_w[0:256,:]
//           B[h,n,:] = feats[h,n,:] @ fc_out_w[256:512,:]
// feats[h,n,d] = memory_w[n*2048 + h*256 + d]
// grid: 256 blocks = (h, ntile of 4), 256 threads (output col)
// ---------------------------------------------------------------------------
__global__ __launch_bounds__(256) void k_featproj(
    const float* __restrict__ memory_w, const float* __restrict__ fc_out_w,
    float* __restrict__ A, float* __restrict__ Bm) {
    int blk = blockIdx.x;
    int h = blk >> 5, n0 = (blk & 31) * 4;
    int t = threadIdx.x;
    __shared__ float f[4 * 256];
    #pragma unroll
    for (int ii = 0; ii < 4; ++ii) {
        int fi = t + ii * 256;
        int r = fi >> 8, d = fi & 255;
        f[fi] = memory_w[(n0 + r) * 2048 + h * 256 + d];
    }
    __syncthreads();
    float a[4] = {}, b[4] = {};
    #pragma unroll 4
    for (int d = 0; d < 256; ++d) {
        float wt = fc_out_w[d * 256 + t];
        float wb = fc_out_w[(d + 256) * 256 + t];
        #pragma unroll
        for (int r = 0; r < 4; ++r) {
            a[r] += f[r * 256 + d] * wt;
            b[r] += f[r * 256 + d] * wb;
        }
    }
    #pragma unroll
    for (int r = 0; r < 4; ++r) {
        A[(h * 128 + n0 + r) * 256 + t] = a[r];
        Bm[(h * 128 + n0 + r) * 256 + t] = b[r];
    }
}

// ---------------------------------------------------------------------------
// Kernel 2: conn[h,i,j] = 1 if (l1+g1) > (l0+g0) else 0
// grid: 512 blocks = (h, i-pair), 256 threads = (di in 0..1) x (j in 0..127)
// ---------------------------------------------------------------------------
__global__ __launch_bounds__(256) void k_conn(
    const float* __restrict__ A, const float* __restrict__ Bm,
    const float* __restrict__ fc_out_b, const float* __restrict__ fc_cat_w,
    const float* __restrict__ fc_cat_b, const float* __restrict__ gumbel_u,
    float* __restrict__ conn) {
    int blk = blockIdx.x;
    int h = blk >> 6, i0 = (blk & 63) * 2;
    int t = threadIdx.x;
    int j = t & 127, di = t >> 7;
    int i = i0 + di;
    __shared__ float sB[2 * 256];
    __shared__ float sw0[256], sw1[256];
    {
        float fb = fc_out_b[t];
        sB[t]       = Bm[(h * 128 + i0) * 256 + t] + fb;
        sB[256 + t] = Bm[(h * 128 + i0 + 1) * 256 + t] + fb;
        sw0[t] = fc_cat_w[t * 2];
        sw1[t] = fc_cat_w[t * 2 + 1];
    }
    __syncthreads();
    const float4* Arow4 = (const float4*)(A + (h * 128 + j) * 256);
    const float* sBr = sB + di * 256;
    float l0 = fc_cat_b[0], l1 = fc_cat_b[1];
    #pragma unroll 4
    for (int d4 = 0; d4 < 64; ++d4) {
        float4 av = Arow4[d4];
        int d = d4 * 4;
        float h0 = fmaxf(av.x + sBr[d + 0], 0.f);
        float h1 = fmaxf(av.y + sBr[d + 1], 0.f);
        float h2 = fmaxf(av.z + sBr[d + 2], 0.f);
        float h3 = fmaxf(av.w + sBr[d + 3], 0.f);
        l0 += h0 * sw0[d] + h1 * sw0[d + 1] + h2 * sw0[d + 2] + h3 * sw0[d + 3];
        l1 += h0 * sw1[d] + h1 * sw1[d + 1] + h2 * sw1[d + 2] + h3 * sw1[d + 3];
    }
    int gb = ((h * 128 + i) * 128 + j) * 2;
    float u0 = gumbel_u[gb], u1 = gumbel_u[gb + 1];
    float g0 = -logf(-logf(u0 + 1e-10f) + 1e-10f);
    float g1 = -logf(-logf(u1 + 1e-10f) + 1e-10f);
    conn[(h * 128 + i) * 128 + j] = ((l1 + g1) > (l0 + g0)) ? 1.f : 0.f;
}

// ---------------------------------------------------------------------------
// Kernel 3: Y[M,256] = act(X[M,256] @ W[256,256] + bias), ACT 0=none 1=gelu
// grid: 256 blocks of 16 rows; 512 threads; each thread = 2 rows x 4 cols.
// ---------------------------------------------------------------------------
template <int ACT>
__global__ __launch_bounds__(512) void k_rowgemm(
    const float* __restrict__ X, const float* __restrict__ W,
    const float* __restrict__ bias, float* __restrict__ Y) {
    __shared__ float xs[16 * 256];
    int t = threadIdx.x;
    int r0 = blockIdx.x * 16;
    #pragma unroll
    for (int ii = 0; ii < 2; ++ii) {
        int fi = t + ii * 512;
        int row = fi >> 6, c4 = (fi & 63) * 4;
        *(float4*)(xs + row * 256 + c4) = *(const float4*)(X + (r0 + row) * 256 + c4);
    }
    __syncthreads();
    int tc = (t & 63) * 4;
    int tr = (t >> 6) * 2;
    float acc0[4] = {}, acc1[4] = {};
    const float* Wp = W + tc;
    const float* x0p = xs + tr * 256;
    #pragma unroll 8
    for (int k = 0; k < 256; ++k) {
        float4 w = *(const float4*)(Wp + k * 256);
        float x0 = x0p[k], x1 = x0p[256 + k];
        acc0[0] += x0 * w.x; acc0[1] += x0 * w.y; acc0[2] += x0 * w.z; acc0[3] += x0 * w.w;
        acc1[0] += x1 * w.x; acc1[1] += x1 * w.y; acc1[2] += x1 * w.z; acc1[3] += x1 * w.w;
    }
    float4 bv = *(const float4*)(bias + tc);
    float o00 = acc0[0] + bv.x, o01 = acc0[1] + bv.y, o02 = acc0[2] + bv.z, o03 = acc0[3] + bv.w;
    float o10 = acc1[0] + bv.x, o11 = acc1[1] + bv.y, o12 = acc1[2] + bv.z, o13 = acc1[3] + bv.w;
    if (ACT == 1) {
        o00 = gelu_f(o00); o01 = gelu_f(o01); o02 = gelu_f(o02); o03 = gelu_f(o03);
        o10 = gelu_f(o10); o11 = gelu_f(o11); o12 = gelu_f(o12); o13 = gelu_f(o13);
    }
    float4 oa = {o00, o01, o02, o03};
    float4 ob = {o10, o11, o12, o13};
    *(float4*)(Y + (r0 + tr) * 256 + tc) = oa;
    *(float4*)(Y + (r0 + tr + 1) * 256 + tc) = ob;
}

// ---------------------------------------------------------------------------
// Kernel 3b: fused q/k/v projection. Three outputs from one staged X tile.
// Same geometry as k_rowgemm.
// ---------------------------------------------------------------------------
__global__ __launch_bounds__(512) void k_qkv(
    const float* __restrict__ X,
    const float* __restrict__ Wq, const float* __restrict__ Bq,
    const float* __restrict__ Wk, const float* __restrict__ Bk,
    const float* __restrict__ Wv, const float* __restrict__ Bv,
    float* __restrict__ Q, float* __restrict__ K, float* __restrict__ V) {
    __shared__ float xs[16 * 256];
    int t = threadIdx.x;
    int r0 = blockIdx.x * 16;
    #pragma unroll
    for (int ii = 0; ii < 2; ++ii) {
        int fi = t + ii * 512;
        int row = fi >> 6, c4 = (fi & 63) * 4;
        *(float4*)(xs + row * 256 + c4) = *(const float4*)(X + (r0 + row) * 256 + c4);
    }
    __syncthreads();
    int tc = (t & 63) * 4;
    int tr = (t >> 6) * 2;
    float aq0[4] = {}, aq1[4] = {}, ak0[4] = {}, ak1[4] = {}, av0[4] = {}, av1[4] = {};
    const float* Wqp = Wq + tc;
    const float* Wkp = Wk + tc;
    const float* Wvp = Wv + tc;
    const float* x0p = xs + tr * 256;
    #pragma unroll 4
    for (int k = 0; k < 256; ++k) {
        float4 wq = *(const float4*)(Wqp + k * 256);
        float4 wk = *(const float4*)(Wkp + k * 256);
        float4 wv = *(const float4*)(Wvp + k * 256);
        float x0 = x0p[k], x1 = x0p[256 + k];
        aq0[0] += x0 * wq.x; aq0[1] += x0 * wq.y; aq0[2] += x0 * wq.z; aq0[3] += x0 * wq.w;
        aq1[0] += x1 * wq.x; aq1[1] += x1 * wq.y; aq1[2] += x1 * wq.z; aq1[3] += x1 * wq.w;
        ak0[0] += x0 * wk.x; ak0[1] += x0 * wk.y; ak0[2] += x0 * wk.z; ak0[3] += x0 * wk.w;
        ak1[0] += x1 * wk.x; ak1[1] += x1 * wk.y; ak1[2] += x1 * wk.z; ak1[3] += x1 * wk.w;
        av0[0] += x0 * wv.x; av0[1] += x0 * wv.y; av0[2] += x0 * wv.z; av0[3] += x0 * wv.w;
        av1[0] += x1 * wv.x; av1[1] += x1 * wv.y; av1[2] += x1 * wv.z; av1[3] += x1 * wv.w;
    }
    float4 bq = *(const float4*)(Bq + tc);
    float4 bk = *(const float4*)(Bk + tc);
    float4 bv = *(const float4*)(Bv + tc);
    float4 o;
    o = {aq0[0]+bq.x, aq0[1]+bq.y, aq0[2]+bq.z, aq0[3]+bq.w}; *(float4*)(Q + (r0+tr)*256 + tc) = o;
    o = {aq1[0]+bq.x, aq1[1]+bq.y, aq1[2]+bq.z, aq1[3]+bq.w}; *(float4*)(Q + (r0+tr+1)*256 + tc) = o;
    o = {ak0[0]+bk.x, ak0[1]+bk.y, ak0[2]+bk.z, ak0[3]+bk.w}; *(float4*)(K + (r0+tr)*256 + tc) = o;
    o = {ak1[0]+bk.x, ak1[1]+bk.y, ak1[2]+bk.z, ak1[3]+bk.w}; *(float4*)(K + (r0+tr+1)*256 + tc) = o;
    o = {av0[0]+bv.x, av0[1]+bv.y, av0[2]+bv.z, av0[3]+bv.w}; *(float4*)(V + (r0+tr)*256 + tc) = o;
    o = {av1[0]+bv.x, av1[1]+bv.y, av1[2]+bv.z, av1[3]+bv.w}; *(float4*)(V + (r0+tr+1)*256 + tc) = o;
}

// ---------------------------------------------------------------------------
// Kernel 4: masked attention. grid: 1024 blocks = (b,h,row-quarter),
// 256 threads = 4 waves; each wave handles 8 query rows.
// ---------------------------------------------------------------------------
__global__ __launch_bounds__(256) void k_attn(
    const float* __restrict__ Q, const float* __restrict__ K,
    const float* __restrict__ V, const float* __restrict__ conn,
    float* __restrict__ AO) {
    int blk = blockIdx.x;
    int bh = blk >> 2, rq = blk & 3;
    int b = bh >> 3, h = bh & 7;
    int r0 = rq * 32;
    int t = threadIdx.x;
    int lane = t & 63, wv = t >> 6;
    __shared__ float qs[32 * 32];
    __shared__ float kT[32 * 129];  // transposed + padded
    __shared__ float vs[128 * 32];
    __shared__ float ps[4][128];
    for (int idx = t; idx < 4096; idx += 256) {
        int r = idx >> 5, d = idx & 31;
        int g = b * 32768 + r * 256 + h * 32 + d;
        vs[idx] = V[g];
        kT[d * 129 + r] = K[g];
    }
    for (int idx = t; idx < 1024; idx += 256) {
        int r = idx >> 5, d = idx & 31;
        qs[idx] = Q[b * 32768 + (r0 + r) * 256 + h * 32 + d];
    }
    __syncthreads();
    const float scale = 0.17677669529663687f;  // 32^-0.5
    for (int rr = wv; rr < 32; rr += 4) {
        int r = r0 + rr;
        int j1 = lane, j2 = lane + 64;
        float s1 = 0.f, s2 = 0.f;
        #pragma unroll
        for (int d = 0; d < 32; ++d) {
            float qv = qs[rr * 32 + d];
            s1 += qv * kT[d * 129 + j1];
            s2 += qv * kT[d * 129 + j2];
        }
        const float* cr = conn + h * 16384 + r * 128;
        s1 = s1 * scale + (cr[j1] - 1.f) * 1e9f;
        s2 = s2 * scale + (cr[j2] - 1.f) * 1e9f;
        float m = fmaxf(s1, s2);
        #pragma unroll
        for (int off = 32; off > 0; off >>= 1) m = fmaxf(m, __shfl_xor(m, off));
        float e1 = expf(s1 - m), e2 = expf(s2 - m);
        float sm = e1 + e2;
        #pragma unroll
        for (int off = 32; off > 0; off >>= 1) sm += __shfl_xor(sm, off);
        ps[wv][j1] = e1;
        ps[wv][j2] = e2;
        float inv = 1.f / sm;
        int d = lane & 31, jq = lane >> 5;
        float acc = 0.f;
        #pragma unroll 8
        for (int jj = 0; jj < 64; ++jj) {
            int j = jq * 64 + jj;
            acc += ps[wv][j] * vs[j * 32 + d];
        }
        acc += __shfl_xor(acc, 32);
        if (lane < 32) AO[b * 32768 + r * 256 + h * 32 + d] = acc * inv;
    }
}

// ---------------------------------------------------------------------------
extern "C" void kernel_launch(void* const* d_in, const int* in_sizes, int n_in,
                              void* d_out, int out_size, void* d_ws, size_t ws_size,
                              hipStream_t stream) {
    const float* x        = (const float*)d_in[0];
    const float* gumbel_u = (const float*)d_in[1];
    const float* memory_w = (const float*)d_in[2];
    const float* fc_out_w = (const float*)d_in[3];
    const float* fc_out_b = (const float*)d_in[4];
    const float* fc_cat_w = (const float*)d_in[5];
    const float* fc_cat_b = (const float*)d_in[6];
    const float* wq       = (const float*)d_in[7];
    const float* bq       = (const float*)d_in[8];
    const float* wk       = (const float*)d_in[9];
    const float* bk       = (const float*)d_in[10];
    const float* wv_      = (const float*)d_in[11];
    const float* bv_      = (const float*)d_in[12];
    const float* out_w    = (const float*)d_in[13];
    const float* out_b    = (const float*)d_in[14];
    const float* mlp_w1   = (const float*)d_in[15];
    const float* mlp_b1   = (const float*)d_in[16];
    const float* mlp_w2   = (const float*)d_in[17];
    const float* mlp_b2   = (const float*)d_in[18];

    float* ws   = (float*)d_ws;
    float* A    = ws;                 //  262144 floats
    float* Bm   = ws + 262144;        //  262144
    float* conn = ws + 524288;        //  131072
    float* hbuf = ws + 655360;        // 1048576 (mlp hidden; reused as attn out)
    float* xm   = ws + 1703936;       // 1048576
    float* q    = ws + 2752512;       // 1048576
    float* k    = ws + 3801088;       // 1048576
    float* v    = ws + 4849664;       // 1048576
    float* ao   = hbuf;
    float* out  = (float*)d_out;

    k_featproj<<<dim3(256), dim3(256), 0, stream>>>(memory_w, fc_out_w, A, Bm);
    k_conn<<<dim3(512), dim3(256), 0, stream>>>(A, Bm, fc_out_b, fc_cat_w, fc_cat_b,
                                                gumbel_u, conn);
    k_rowgemm<1><<<dim3(256), dim3(512), 0, stream>>>(x, mlp_w1, mlp_b1, hbuf);
    k_rowgemm<0><<<dim3(256), dim3(512), 0, stream>>>(hbuf, mlp_w2, mlp_b2, xm);
    k_qkv<<<dim3(256), dim3(512), 0, stream>>>(xm, wq, bq, wk, bk, wv_, bv_, q, k, v);
    k_attn<<<dim3(1024), dim3(256), 0, stream>>>(q, k, v, conn, ao);
    k_rowgemm<0><<<dim3(256), dim3(512), 0, stream>>>(ao, out_w, out_b, out);
}

// Round 3
// 217.097 us; speedup vs baseline: 1.4938x; 1.4361x over previous
//
#include <hip/hip_runtime.h>
#include <hip/hip_bf16.h>
#include <math.h>

// Problem constants: H=8, d_model=256, N=128, d_k=32, B=32, rows=4096

typedef short short8 __attribute__((ext_vector_type(8)));
typedef float f32x4 __attribute__((ext_vector_type(4)));

union V8 { uint4 u; short8 s; };

__device__ __forceinline__ float gelu_f(float x) {
    float inner = 0.7978845608028654f * (x + 0.044715f * x * x * x);
    return 0.5f * x * (1.0f + tanhf(inner));
}

__device__ __forceinline__ void split_bf16(float x, ushort& h, ushort& l) {
    __hip_bfloat16 bh = __float2bfloat16(x);          // RN
    float hf = __bfloat162float(bh);
    __hip_bfloat16 bl = __float2bfloat16(x - hf);
    h = __builtin_bit_cast(ushort, bh);
    l = __builtin_bit_cast(ushort, bl);
}

__device__ __forceinline__ short8 lds_frag(const ushort* p) {
    V8 v; v.u = *(const uint4*)p; return v.s;
}

// ---------------------------------------------------------------------------
// Weight prep: W[256k x 256n] fp32 -> fragment-ordered bf16 hi/lo.
// Element (k,n) stored at  ((( (n>>4)*8 + (k>>5) )*64 + (((k>>3)&3)<<4 | (n&15)) )*8 + (k&7)
// so a wave's B-frag load for (coltile tg, kstep ks) is uint4 at [(tg*8+ks)*64 + lane].
// grid 96 = 6 matrices x 16 col-tiles, 256 threads.
// ---------------------------------------------------------------------------
__global__ __launch_bounds__(256) void k_wprep(
    const float* __restrict__ w0, const float* __restrict__ w1,
    const float* __restrict__ w2, const float* __restrict__ w3,
    const float* __restrict__ w4, const float* __restrict__ w5,
    ushort* __restrict__ hi, ushort* __restrict__ lo) {
    int m = blockIdx.x >> 4, tn = blockIdx.x & 15;
    const float* W = m == 0 ? w0 : m == 1 ? w1 : m == 2 ? w2 : m == 3 ? w3 : m == 4 ? w4 : w5;
    ushort* Hm = hi + m * 65536;
    ushort* Lm = lo + m * 65536;
    int t = threadIdx.x;
    int n = tn * 16 + (t & 15);
    int k0 = (t >> 4) * 16;
    ushort hb[16], lb[16];
    #pragma unroll
    for (int kk = 0; kk < 16; ++kk)
        split_bf16(W[(k0 + kk) * 256 + n], hb[kk], lb[kk]);
    int ks = k0 >> 5;
    int q0 = (k0 >> 3) & 3;
    #pragma unroll
    for (int rb = 0; rb < 2; ++rb) {
        int lane = ((q0 + rb) << 4) | (t & 15);
        int idx = ((tn * 8 + ks) * 64 + lane) * 8;
        const ushort* hp = hb + rb * 8;
        const ushort* lp = lb + rb * 8;
        uint4 ph = { (uint)hp[0] | ((uint)hp[1] << 16), (uint)hp[2] | ((uint)hp[3] << 16),
                     (uint)hp[4] | ((uint)hp[5] << 16), (uint)hp[6] | ((uint)hp[7] << 16) };
        uint4 pl = { (uint)lp[0] | ((uint)lp[1] << 16), (uint)lp[2] | ((uint)lp[3] << 16),
                     (uint)lp[4] | ((uint)lp[5] << 16), (uint)lp[6] | ((uint)lp[7] << 16) };
        *(uint4*)(Hm + idx) = ph;
        *(uint4*)(Lm + idx) = pl;
    }
}

// ---------------------------------------------------------------------------
// MFMA GEMM: Y[M,256] = act(X @ W + b), X fp32 staged to LDS as bf16 hi/lo.
// Grid 256 blocks x 16 rows; 256 threads = 4 waves; wave w does cols w*64..+63
// as 4 col-tiles of 16; K loop = 8 steps of 32. 3 MFMAs per product (hi/lo).
// ---------------------------------------------------------------------------
template <int ACT>
__global__ __launch_bounds__(256) void k_gemm16(
    const float* __restrict__ X, const ushort* __restrict__ Whi,
    const ushort* __restrict__ Wlo, const float* __restrict__ bias,
    float* __restrict__ Y) {
    __shared__ ushort xhi[16 * 264], xlo[16 * 264];
    int t = threadIdx.x;
    int r0 = blockIdx.x * 16;
    #pragma unroll
    for (int ii = 0; ii < 4; ++ii) {
        int f4 = ii * 256 + t;
        int row = f4 >> 6, c = (f4 & 63) * 4;
        float4 xv = *(const float4*)(X + (r0 + row) * 256 + c);
        ushort h[4], l[4];
        split_bf16(xv.x, h[0], l[0]); split_bf16(xv.y, h[1], l[1]);
        split_bf16(xv.z, h[2], l[2]); split_bf16(xv.w, h[3], l[3]);
        uint2 ph = { (uint)h[0] | ((uint)h[1] << 16), (uint)h[2] | ((uint)h[3] << 16) };
        uint2 pl = { (uint)l[0] | ((uint)l[1] << 16), (uint)l[2] | ((uint)l[3] << 16) };
        *(uint2*)(xhi + row * 264 + c) = ph;
        *(uint2*)(xlo + row * 264 + c) = pl;
    }
    __syncthreads();
    int l = t & 63, w = t >> 6;
    int lr = l & 15, quad = l >> 4;
    const ushort* ah = xhi + lr * 264 + quad * 8;
    const ushort* al = xlo + lr * 264 + quad * 8;
    const uint4* H4 = (const uint4*)Whi;
    const uint4* L4 = (const uint4*)Wlo;
    f32x4 acc[4] = {};
    #pragma unroll 2
    for (int ks = 0; ks < 8; ++ks) {
        short8 a_h = lds_frag(ah + ks * 32);
        short8 a_l = lds_frag(al + ks * 32);
        #pragma unroll
        for (int ti = 0; ti < 4; ++ti) {
            int tg = w * 4 + ti;
            V8 bh, bl;
            bh.u = H4[(tg * 8 + ks) * 64 + l];
            bl.u = L4[(tg * 8 + ks) * 64 + l];
            acc[ti] = __builtin_amdgcn_mfma_f32_16x16x32_bf16(a_h, bh.s, acc[ti], 0, 0, 0);
            acc[ti] = __builtin_amdgcn_mfma_f32_16x16x32_bf16(a_l, bh.s, acc[ti], 0, 0, 0);
            acc[ti] = __builtin_amdgcn_mfma_f32_16x16x32_bf16(a_h, bl.s, acc[ti], 0, 0, 0);
        }
    }
    #pragma unroll
    for (int ti = 0; ti < 4; ++ti) {
        int n0 = (w * 4 + ti) * 16 + lr;
        float bs = bias[n0];
        #pragma unroll
        for (int r = 0; r < 4; ++r) {
            float o = acc[ti][r] + bs;
            if (ACT) o = gelu_f(o);
            Y[(r0 + quad * 4 + r) * 256 + n0] = o;
        }
    }
}

// ---------------------------------------------------------------------------
// Fused q/k/v MFMA GEMM: same geometry, 3 weight sets share A-frags.
// ---------------------------------------------------------------------------
__global__ __launch_bounds__(256) void k_qkv16(
    const float* __restrict__ X,
    const ushort* __restrict__ Whi, const ushort* __restrict__ Wlo,
    const float* __restrict__ Bq, const float* __restrict__ Bk,
    const float* __restrict__ Bv,
    float* __restrict__ Q, float* __restrict__ K, float* __restrict__ V) {
    __shared__ ushort xhi[16 * 264], xlo[16 * 264];
    int t = threadIdx.x;
    int r0 = blockIdx.x * 16;
    #pragma unroll
    for (int ii = 0; ii < 4; ++ii) {
        int f4 = ii * 256 + t;
        int row = f4 >> 6, c = (f4 & 63) * 4;
        float4 xv = *(const float4*)(X + (r0 + row) * 256 + c);
        ushort h[4], l[4];
        split_bf16(xv.x, h[0], l[0]); split_bf16(xv.y, h[1], l[1]);
        split_bf16(xv.z, h[2], l[2]); split_bf16(xv.w, h[3], l[3]);
        uint2 ph = { (uint)h[0] | ((uint)h[1] << 16), (uint)h[2] | ((uint)h[3] << 16) };
        uint2 pl = { (uint)l[0] | ((uint)l[1] << 16), (uint)l[2] | ((uint)l[3] << 16) };
        *(uint2*)(xhi + row * 264 + c) = ph;
        *(uint2*)(xlo + row * 264 + c) = pl;
    }
    __syncthreads();
    int l = t & 63, w = t >> 6;
    int lr = l & 15, quad = l >> 4;
    const ushort* ah = xhi + lr * 264 + quad * 8;
    const ushort* al = xlo + lr * 264 + quad * 8;
    // matrix offsets inside packed weight area: q=2, k=3, v=4 (x65536)
    const uint4* Hq = (const uint4*)(Whi + 2 * 65536);
    const uint4* Lq = (const uint4*)(Wlo + 2 * 65536);
    const uint4* Hk = (const uint4*)(Whi + 3 * 65536);
    const uint4* Lk = (const uint4*)(Wlo + 3 * 65536);
    const uint4* Hv = (const uint4*)(Whi + 4 * 65536);
    const uint4* Lv = (const uint4*)(Wlo + 4 * 65536);
    f32x4 aq[4] = {}, ak[4] = {}, av[4] = {};
    #pragma unroll 1
    for (int ks = 0; ks < 8; ++ks) {
        short8 a_h = lds_frag(ah + ks * 32);
        short8 a_l = lds_frag(al + ks * 32);
        #pragma unroll
        for (int ti = 0; ti < 4; ++ti) {
            int off = ((w * 4 + ti) * 8 + ks) * 64 + l;
            V8 qh, ql, kh, kl, vh, vl;
            qh.u = Hq[off]; ql.u = Lq[off];
            kh.u = Hk[off]; kl.u = Lk[off];
            vh.u = Hv[off]; vl.u = Lv[off];
            aq[ti] = __builtin_amdgcn_mfma_f32_16x16x32_bf16(a_h, qh.s, aq[ti], 0, 0, 0);
            aq[ti] = __builtin_amdgcn_mfma_f32_16x16x32_bf16(a_l, qh.s, aq[ti], 0, 0, 0);
            aq[ti] = __builtin_amdgcn_mfma_f32_16x16x32_bf16(a_h, ql.s, aq[ti], 0, 0, 0);
            ak[ti] = __builtin_amdgcn_mfma_f32_16x16x32_bf16(a_h, kh.s, ak[ti], 0, 0, 0);
            ak[ti] = __builtin_amdgcn_mfma_f32_16x16x32_bf16(a_l, kh.s, ak[ti], 0, 0, 0);
            ak[ti] = __builtin_amdgcn_mfma_f32_16x16x32_bf16(a_h, kl.s, ak[ti], 0, 0, 0);
            av[ti] = __builtin_amdgcn_mfma_f32_16x16x32_bf16(a_h, vh.s, av[ti], 0, 0, 0);
            av[ti] = __builtin_amdgcn_mfma_f32_16x16x32_bf16(a_l, vh.s, av[ti], 0, 0, 0);
            av[ti] = __builtin_amdgcn_mfma_f32_16x16x32_bf16(a_h, vl.s, av[ti], 0, 0, 0);
        }
    }
    #pragma unroll
    for (int ti = 0; ti < 4; ++ti) {
        int n0 = (w * 4 + ti) * 16 + lr;
        float bq = Bq[n0], bk = Bk[n0], bv = Bv[n0];
        #pragma unroll
        for (int r = 0; r < 4; ++r) {
            int go = (r0 + quad * 4 + r) * 256 + n0;
            Q[go] = aq[ti][r] + bq;
            K[go] = ak[ti][r] + bk;
            V[go] = av[ti][r] + bv;
        }
    }
}

// ---------------------------------------------------------------------------
// Kernel 1: A[h,n,:] / B[h,n,:] = feats @ fc_out_w halves.
// feats[h,n,d] = memory_w[n*2048 + h*256 + d]
// ---------------------------------------------------------------------------
__global__ __launch_bounds__(256) void k_featproj(
    const float* __restrict__ memory_w, const float* __restrict__ fc_out_w,
    float* __restrict__ A, float* __restrict__ Bm) {
    int blk = blockIdx.x;
    int h = blk >> 5, n0 = (blk & 31) * 4;
    int t = threadIdx.x;
    __shared__ float f[4 * 256];
    #pragma unroll
    for (int ii = 0; ii < 4; ++ii) {
        int fi = t + ii * 256;
        int r = fi >> 8, d = fi & 255;
        f[fi] = memory_w[(n0 + r) * 2048 + h * 256 + d];
    }
    __syncthreads();
    float a[4] = {}, b[4] = {};
    #pragma unroll 4
    for (int d = 0; d < 256; ++d) {
        float wt = fc_out_w[d * 256 + t];
        float wb = fc_out_w[(d + 256) * 256 + t];
        #pragma unroll
        for (int r = 0; r < 4; ++r) {
            a[r] += f[r * 256 + d] * wt;
            b[r] += f[r * 256 + d] * wb;
        }
    }
    #pragma unroll
    for (int r = 0; r < 4; ++r) {
        A[(h * 128 + n0 + r) * 256 + t] = a[r];
        Bm[(h * 128 + n0 + r) * 256 + t] = b[r];
    }
}

// ---------------------------------------------------------------------------
// Kernel 2: conn[h,i,j] = (l1+g1) > (l0+g0)
// grid 512 = (h, i-pair), 256 threads = (di) x (j)
// ---------------------------------------------------------------------------
__global__ __launch_bounds__(256) void k_conn(
    const float* __restrict__ A, const float* __restrict__ Bm,
    const float* __restrict__ fc_out_b, const float* __restrict__ fc_cat_w,
    const float* __restrict__ fc_cat_b, const float* __restrict__ gumbel_u,
    float* __restrict__ conn) {
    int blk = blockIdx.x;
    int h = blk >> 6, i0 = (blk & 63) * 2;
    int t = threadIdx.x;
    int j = t & 127, di = t >> 7;
    int i = i0 + di;
    __shared__ float sB[2 * 256];
    __shared__ float sw0[256], sw1[256];
    {
        float fb = fc_out_b[t];
        sB[t]       = Bm[(h * 128 + i0) * 256 + t] + fb;
        sB[256 + t] = Bm[(h * 128 + i0 + 1) * 256 + t] + fb;
        sw0[t] = fc_cat_w[t * 2];
        sw1[t] = fc_cat_w[t * 2 + 1];
    }
    __syncthreads();
    const float4* Arow4 = (const float4*)(A + (h * 128 + j) * 256);
    const float* sBr = sB + di * 256;
    float l0 = fc_cat_b[0], l1 = fc_cat_b[1];
    #pragma unroll 4
    for (int d4 = 0; d4 < 64; ++d4) {
        float4 av = Arow4[d4];
        int d = d4 * 4;
        float h0 = fmaxf(av.x + sBr[d + 0], 0.f);
        float h1 = fmaxf(av.y + sBr[d + 1], 0.f);
        float h2 = fmaxf(av.z + sBr[d + 2], 0.f);
        float h3 = fmaxf(av.w + sBr[d + 3], 0.f);
        l0 += h0 * sw0[d] + h1 * sw0[d + 1] + h2 * sw0[d + 2] + h3 * sw0[d + 3];
        l1 += h0 * sw1[d] + h1 * sw1[d + 1] + h2 * sw1[d + 2] + h3 * sw1[d + 3];
    }
    int gb = ((h * 128 + i) * 128 + j) * 2;
    float u0 = gumbel_u[gb], u1 = gumbel_u[gb + 1];
    float g0 = -logf(-logf(u0 + 1e-10f) + 1e-10f);
    float g1 = -logf(-logf(u1 + 1e-10f) + 1e-10f);
    conn[(h * 128 + i) * 128 + j] = ((l1 + g1) > (l0 + g0)) ? 1.f : 0.f;
}

// ---------------------------------------------------------------------------
// Kernel 4: masked attention. grid 1024 = (b,h,row-quarter), 256 threads.
// ---------------------------------------------------------------------------
__global__ __launch_bounds__(256) void k_attn(
    const float* __restrict__ Q, const float* __restrict__ K,
    const float* __restrict__ V, const float* __restrict__ conn,
    float* __restrict__ AO) {
    int blk = blockIdx.x;
    int bh = blk >> 2, rq = blk & 3;
    int b = bh >> 3, h = bh & 7;
    int r0 = rq * 32;
    int t = threadIdx.x;
    int lane = t & 63, wv = t >> 6;
    __shared__ float qs[32 * 32];
    __shared__ float kT[32 * 129];
    __shared__ float vs[128 * 32];
    __shared__ float ps[4][128];
    for (int idx = t; idx < 4096; idx += 256) {
        int r = idx >> 5, d = idx & 31;
        int g = b * 32768 + r * 256 + h * 32 + d;
        vs[idx] = V[g];
        kT[d * 129 + r] = K[g];
    }
    for (int idx = t; idx < 1024; idx += 256) {
        int r = idx >> 5, d = idx & 31;
        qs[idx] = Q[b * 32768 + (r0 + r) * 256 + h * 32 + d];
    }
    __syncthreads();
    const float scale = 0.17677669529663687f;  // 32^-0.5
    for (int rr = wv; rr < 32; rr += 4) {
        int r = r0 + rr;
        int j1 = lane, j2 = lane + 64;
        float s1 = 0.f, s2 = 0.f;
        #pragma unroll
        for (int d = 0; d < 32; ++d) {
            float qv = qs[rr * 32 + d];
            s1 += qv * kT[d * 129 + j1];
            s2 += qv * kT[d * 129 + j2];
        }
        const float* cr = conn + h * 16384 + r * 128;
        s1 = s1 * scale + (cr[j1] - 1.f) * 1e9f;
        s2 = s2 * scale + (cr[j2] - 1.f) * 1e9f;
        float m = fmaxf(s1, s2);
        #pragma unroll
        for (int off = 32; off > 0; off >>= 1) m = fmaxf(m, __shfl_xor(m, off));
        float e1 = expf(s1 - m), e2 = expf(s2 - m);
        float sm = e1 + e2;
        #pragma unroll
        for (int off = 32; off > 0; off >>= 1) sm += __shfl_xor(sm, off);
        ps[wv][j1] = e1;
        ps[wv][j2] = e2;
        float inv = 1.f / sm;
        int d = lane & 31, jq = lane >> 5;
        float acc = 0.f;
        #pragma unroll 8
        for (int jj = 0; jj < 64; ++jj) {
            int j = jq * 64 + jj;
            acc += ps[wv][j] * vs[j * 32 + d];
        }
        acc += __shfl_xor(acc, 32);
        if (lane < 32) AO[b * 32768 + r * 256 + h * 32 + d] = acc * inv;
    }
}

// ---------------------------------------------------------------------------
extern "C" void kernel_launch(void* const* d_in, const int* in_sizes, int n_in,
                              void* d_out, int out_size, void* d_ws, size_t ws_size,
                              hipStream_t stream) {
    const float* x        = (const float*)d_in[0];
    const float* gumbel_u = (const float*)d_in[1];
    const float* memory_w = (const float*)d_in[2];
    const float* fc_out_w = (const float*)d_in[3];
    const float* fc_out_b = (const float*)d_in[4];
    const float* fc_cat_w = (const float*)d_in[5];
    const float* fc_cat_b = (const float*)d_in[6];
    const float* wq       = (const float*)d_in[7];
    const float* bq       = (const float*)d_in[8];
    const float* wk       = (const float*)d_in[9];
    const float* bk       = (const float*)d_in[10];
    const float* wv_      = (const float*)d_in[11];
    const float* bv_      = (const float*)d_in[12];
    const float* out_w    = (const float*)d_in[13];
    const float* out_b    = (const float*)d_in[14];
    const float* mlp_w1   = (const float*)d_in[15];
    const float* mlp_b1   = (const float*)d_in[16];
    const float* mlp_w2   = (const float*)d_in[17];
    const float* mlp_b2   = (const float*)d_in[18];

    float* ws   = (float*)d_ws;
    float* A    = ws;                 //  262144 floats
    float* Bm   = ws + 262144;        //  262144
    float* conn = ws + 524288;        //  131072
    float* hbuf = ws + 655360;        // 1048576 (mlp hidden; reused as attn out)
    float* xm   = ws + 1703936;       // 1048576
    float* q    = ws + 2752512;       // 1048576
    float* k    = ws + 3801088;       // 1048576
    float* v    = ws + 4849664;       // 1048576
    float* ao   = hbuf;
    float* out  = (float*)d_out;
    // packed weights: 6 matrices x 65536 ushorts, hi then lo
    ushort* wf_hi = (ushort*)(ws + 5898240);
    ushort* wf_lo = wf_hi + 6 * 65536;

    // weight order: 0=mlp_w1 1=mlp_w2 2=wq 3=wk 4=wv 5=out_w
    k_wprep<<<dim3(96), dim3(256), 0, stream>>>(mlp_w1, mlp_w2, wq, wk, wv_, out_w,
                                                wf_hi, wf_lo);
    k_featproj<<<dim3(256), dim3(256), 0, stream>>>(memory_w, fc_out_w, A, Bm);
    k_conn<<<dim3(512), dim3(256), 0, stream>>>(A, Bm, fc_out_b, fc_cat_w, fc_cat_b,
                                                gumbel_u, conn);
    k_gemm16<1><<<dim3(256), dim3(256), 0, stream>>>(x, wf_hi + 0 * 65536,
                                                     wf_lo + 0 * 65536, mlp_b1, hbuf);
    k_gemm16<0><<<dim3(256), dim3(256), 0, stream>>>(hbuf, wf_hi + 1 * 65536,
                                                     wf_lo + 1 * 65536, mlp_b2, xm);
    k_qkv16<<<dim3(256), dim3(256), 0, stream>>>(xm, wf_hi, wf_lo, bq, bk, bv_, q, k, v);
    k_attn<<<dim3(1024), dim3(256), 0, stream>>>(q, k, v, conn, ao);
    k_gemm16<0><<<dim3(256), dim3(256), 0, stream>>>(ao, wf_hi + 5 * 65536,
                                                     wf_lo + 5 * 65536, out_b, out);
}

// Round 4
// 189.664 us; speedup vs baseline: 1.7099x; 1.1446x over previous
//
#include <hip/hip_runtime.h>
#include <hip/hip_bf16.h>
#include <math.h>

// Problem constants: H=8, d_model=256, N=128, d_k=32, B=32, rows=4096

typedef short short8 __attribute__((ext_vector_type(8)));
typedef float f32x4 __attribute__((ext_vector_type(4)));

union V8 { uint4 u; short8 s; };

__device__ __forceinline__ float gelu_f(float x) {
    float inner = 0.7978845608028654f * (x + 0.044715f * x * x * x);
    return 0.5f * x * (1.0f + tanhf(inner));
}

__device__ __forceinline__ void split_bf16(float x, ushort& h, ushort& l) {
    __hip_bfloat16 bh = __float2bfloat16(x);          // RN
    float hf = __bfloat162float(bh);
    __hip_bfloat16 bl = __float2bfloat16(x - hf);
    h = __builtin_bit_cast(ushort, bh);
    l = __builtin_bit_cast(ushort, bl);
}

__device__ __forceinline__ ushort bf16bits(float x) {
    return __builtin_bit_cast(ushort, __float2bfloat16(x));
}
__device__ __forceinline__ float bits_to_f(ushort v) {
    return __builtin_bit_cast(float, ((uint)v) << 16);
}
__device__ __forceinline__ uint pk(float a, float b) {
    return (uint)bf16bits(a) | ((uint)bf16bits(b) << 16);
}
__device__ __forceinline__ short8 lds_frag(const ushort* p) {
    V8 v; v.u = *(const uint4*)p; return v.s;
}

// ---------------------------------------------------------------------------
// Weight prep: W[256k x 256n] fp32 -> fragment-ordered bf16 hi/lo.
// B-frag for (coltile tg, kstep ks) is uint4 at [(tg*8+ks)*64 + lane].
// grid 96 = 6 matrices x 16 col-tiles, 256 threads.
// ---------------------------------------------------------------------------
__global__ __launch_bounds__(256) void k_wprep(
    const float* __restrict__ w0, const float* __restrict__ w1,
    const float* __restrict__ w2, const float* __restrict__ w3,
    const float* __restrict__ w4, const float* __restrict__ w5,
    ushort* __restrict__ hi, ushort* __restrict__ lo) {
    int m = blockIdx.x >> 4, tn = blockIdx.x & 15;
    const float* W = m == 0 ? w0 : m == 1 ? w1 : m == 2 ? w2 : m == 3 ? w3 : m == 4 ? w4 : w5;
    ushort* Hm = hi + m * 65536;
    ushort* Lm = lo + m * 65536;
    int t = threadIdx.x;
    int n = tn * 16 + (t & 15);
    int k0 = (t >> 4) * 16;
    ushort hb[16], lb[16];
    #pragma unroll
    for (int kk = 0; kk < 16; ++kk)
        split_bf16(W[(k0 + kk) * 256 + n], hb[kk], lb[kk]);
    int ks = k0 >> 5;
    int q0 = (k0 >> 3) & 3;
    #pragma unroll
    for (int rb = 0; rb < 2; ++rb) {
        int lane = ((q0 + rb) << 4) | (t & 15);
        int idx = ((tn * 8 + ks) * 64 + lane) * 8;
        const ushort* hp = hb + rb * 8;
        const ushort* lp = lb + rb * 8;
        uint4 ph = { (uint)hp[0] | ((uint)hp[1] << 16), (uint)hp[2] | ((uint)hp[3] << 16),
                     (uint)hp[4] | ((uint)hp[5] << 16), (uint)hp[6] | ((uint)hp[7] << 16) };
        uint4 pl = { (uint)lp[0] | ((uint)lp[1] << 16), (uint)lp[2] | ((uint)lp[3] << 16),
                     (uint)lp[4] | ((uint)lp[5] << 16), (uint)lp[6] | ((uint)lp[7] << 16) };
        *(uint4*)(Hm + idx) = ph;
        *(uint4*)(Lm + idx) = pl;
    }
}

// ---------------------------------------------------------------------------
// Kernel 1: A[h,n,:] / B[h,n,:] = feats @ fc_out_w halves. fp32 vector.
// ---------------------------------------------------------------------------
__global__ __launch_bounds__(256) void k_featproj(
    const float* __restrict__ memory_w, const float* __restrict__ fc_out_w,
    float* __restrict__ A, float* __restrict__ Bm) {
    int blk = blockIdx.x;
    int h = blk >> 5, n0 = (blk & 31) * 4;
    int t = threadIdx.x;
    __shared__ float f[4 * 256];
    #pragma unroll
    for (int ii = 0; ii < 4; ++ii) {
        int fi = t + ii * 256;
        int r = fi >> 8, d = fi & 255;
        f[fi] = memory_w[(n0 + r) * 2048 + h * 256 + d];
    }
    __syncthreads();
    float a[4] = {}, b[4] = {};
    #pragma unroll 4
    for (int d = 0; d < 256; ++d) {
        float wt = fc_out_w[d * 256 + t];
        float wb = fc_out_w[(d + 256) * 256 + t];
        #pragma unroll
        for (int r = 0; r < 4; ++r) {
            a[r] += f[r * 256 + d] * wt;
            b[r] += f[r * 256 + d] * wb;
        }
    }
    #pragma unroll
    for (int r = 0; r < 4; ++r) {
        A[(h * 128 + n0 + r) * 256 + t] = a[r];
        Bm[(h * 128 + n0 + r) * 256 + t] = b[r];
    }
}

// ---------------------------------------------------------------------------
// Kernel 2: conn[h,i,j] = (l1+g1) > (l0+g0). fp32 (hard threshold — exact).
// ---------------------------------------------------------------------------
__global__ __launch_bounds__(256) void k_conn(
    const float* __restrict__ A, const float* __restrict__ Bm,
    const float* __restrict__ fc_out_b, const float* __restrict__ fc_cat_w,
    const float* __restrict__ fc_cat_b, const float* __restrict__ gumbel_u,
    float* __restrict__ conn) {
    int blk = blockIdx.x;
    int h = blk >> 6, i0 = (blk & 63) * 2;
    int t = threadIdx.x;
    int j = t & 127, di = t >> 7;
    int i = i0 + di;
    __shared__ float sB[2 * 256];
    __shared__ float sw0[256], sw1[256];
    {
        float fb = fc_out_b[t];
        sB[t]       = Bm[(h * 128 + i0) * 256 + t] + fb;
        sB[256 + t] = Bm[(h * 128 + i0 + 1) * 256 + t] + fb;
        sw0[t] = fc_cat_w[t * 2];
        sw1[t] = fc_cat_w[t * 2 + 1];
    }
    __syncthreads();
    const float4* Arow4 = (const float4*)(A + (h * 128 + j) * 256);
    const float* sBr = sB + di * 256;
    float l0 = fc_cat_b[0], l1 = fc_cat_b[1];
    #pragma unroll 4
    for (int d4 = 0; d4 < 64; ++d4) {
        float4 av = Arow4[d4];
        int d = d4 * 4;
        float h0 = fmaxf(av.x + sBr[d + 0], 0.f);
        float h1 = fmaxf(av.y + sBr[d + 1], 0.f);
        float h2 = fmaxf(av.z + sBr[d + 2], 0.f);
        float h3 = fmaxf(av.w + sBr[d + 3], 0.f);
        l0 += h0 * sw0[d] + h1 * sw0[d + 1] + h2 * sw0[d + 2] + h3 * sw0[d + 3];
        l1 += h0 * sw1[d] + h1 * sw1[d + 1] + h2 * sw1[d + 2] + h3 * sw1[d + 3];
    }
    int gb = ((h * 128 + i) * 128 + j) * 2;
    float u0 = gumbel_u[gb], u1 = gumbel_u[gb + 1];
    float g0 = -logf(-logf(u0 + 1e-10f) + 1e-10f);
    float g1 = -logf(-logf(u1 + 1e-10f) + 1e-10f);
    conn[(h * 128 + i) * 128 + j] = ((l1 + g1) > (l0 + g0)) ? 1.f : 0.f;
}

// ---------------------------------------------------------------------------
// Fused mlp1(gelu) -> mlp2 -> q/k/v. 256 blocks x 16 rows, 512 thr = 8 waves.
// Wave w owns cols w*32..w*32+31 (2 col-tiles). LDS hi/lo intermediates.
// Weight order in packed area: 0=mlp_w1 1=mlp_w2 2=wq 3=wk 4=wv 5=out_w.
// ---------------------------------------------------------------------------
__global__ __launch_bounds__(512) void k_fused5(
    const float* __restrict__ X,
    const ushort* __restrict__ Whi, const ushort* __restrict__ Wlo,
    const float* __restrict__ b1, const float* __restrict__ b2,
    const float* __restrict__ Bq, const float* __restrict__ Bk,
    const float* __restrict__ Bv,
    float* __restrict__ Q, float* __restrict__ K, float* __restrict__ V) {
    __shared__ __align__(16) ushort aHi[16 * 264], aLo[16 * 264];
    __shared__ __align__(16) ushort bHi[16 * 264], bLo[16 * 264];
    int t = threadIdx.x;
    int r0 = blockIdx.x * 16;
    // stage X -> aHi/aLo
    #pragma unroll
    for (int ii = 0; ii < 2; ++ii) {
        int f4 = ii * 512 + t;
        int row = f4 >> 6, c = (f4 & 63) * 4;
        float4 xv = *(const float4*)(X + (r0 + row) * 256 + c);
        ushort h[4], l[4];
        split_bf16(xv.x, h[0], l[0]); split_bf16(xv.y, h[1], l[1]);
        split_bf16(xv.z, h[2], l[2]); split_bf16(xv.w, h[3], l[3]);
        uint2 ph = { (uint)h[0] | ((uint)h[1] << 16), (uint)h[2] | ((uint)h[3] << 16) };
        uint2 pl = { (uint)l[0] | ((uint)l[1] << 16), (uint)l[2] | ((uint)l[3] << 16) };
        *(uint2*)(aHi + row * 264 + c) = ph;
        *(uint2*)(aLo + row * 264 + c) = pl;
    }
    __syncthreads();
    int l = t & 63, w = t >> 6;
    int lr = l & 15, quad = l >> 4;
    int aoff = lr * 264 + quad * 8;
    // ---- stage 1: mlp1 + gelu -> bHi/bLo
    {
        const uint4* H4 = (const uint4*)(Whi + 0 * 65536);
        const uint4* L4 = (const uint4*)(Wlo + 0 * 65536);
        f32x4 acc[2] = {};
        #pragma unroll 2
        for (int ks = 0; ks < 8; ++ks) {
            short8 a_h = lds_frag(aHi + aoff + ks * 32);
            short8 a_l = lds_frag(aLo + aoff + ks * 32);
            #pragma unroll
            for (int ti = 0; ti < 2; ++ti) {
                int off = ((w * 2 + ti) * 8 + ks) * 64 + l;
                V8 bh, bl; bh.u = H4[off]; bl.u = L4[off];
                acc[ti] = __builtin_amdgcn_mfma_f32_16x16x32_bf16(a_h, bh.s, acc[ti], 0, 0, 0);
                acc[ti] = __builtin_amdgcn_mfma_f32_16x16x32_bf16(a_l, bh.s, acc[ti], 0, 0, 0);
                acc[ti] = __builtin_amdgcn_mfma_f32_16x16x32_bf16(a_h, bl.s, acc[ti], 0, 0, 0);
            }
        }
        #pragma unroll
        for (int ti = 0; ti < 2; ++ti) {
            int n0 = (w * 2 + ti) * 16 + lr;
            float bb = b1[n0];
            #pragma unroll
            for (int r = 0; r < 4; ++r) {
                float o = gelu_f(acc[ti][r] + bb);
                ushort hh, ll; split_bf16(o, hh, ll);
                int ad = (quad * 4 + r) * 264 + n0;
                bHi[ad] = hh; bLo[ad] = ll;
            }
        }
    }
    __syncthreads();
    // ---- stage 2: mlp2 -> aHi/aLo
    {
        const uint4* H4 = (const uint4*)(Whi + 1 * 65536);
        const uint4* L4 = (const uint4*)(Wlo + 1 * 65536);
        f32x4 acc[2] = {};
        #pragma unroll 2
        for (int ks = 0; ks < 8; ++ks) {
            short8 a_h = lds_frag(bHi + aoff + ks * 32);
            short8 a_l = lds_frag(bLo + aoff + ks * 32);
            #pragma unroll
            for (int ti = 0; ti < 2; ++ti) {
                int off = ((w * 2 + ti) * 8 + ks) * 64 + l;
                V8 bh, bl; bh.u = H4[off]; bl.u = L4[off];
                acc[ti] = __builtin_amdgcn_mfma_f32_16x16x32_bf16(a_h, bh.s, acc[ti], 0, 0, 0);
                acc[ti] = __builtin_amdgcn_mfma_f32_16x16x32_bf16(a_l, bh.s, acc[ti], 0, 0, 0);
                acc[ti] = __builtin_amdgcn_mfma_f32_16x16x32_bf16(a_h, bl.s, acc[ti], 0, 0, 0);
            }
        }
        #pragma unroll
        for (int ti = 0; ti < 2; ++ti) {
            int n0 = (w * 2 + ti) * 16 + lr;
            float bb = b2[n0];
            #pragma unroll
            for (int r = 0; r < 4; ++r) {
                float o = acc[ti][r] + bb;
                ushort hh, ll; split_bf16(o, hh, ll);
                int ad = (quad * 4 + r) * 264 + n0;
                aHi[ad] = hh; aLo[ad] = ll;
            }
        }
    }
    __syncthreads();
    // ---- stage 3: q/k/v -> global
    {
        const uint4* Hq = (const uint4*)(Whi + 2 * 65536);
        const uint4* Lq = (const uint4*)(Wlo + 2 * 65536);
        const uint4* Hk = (const uint4*)(Whi + 3 * 65536);
        const uint4* Lk = (const uint4*)(Wlo + 3 * 65536);
        const uint4* Hv = (const uint4*)(Whi + 4 * 65536);
        const uint4* Lv = (const uint4*)(Wlo + 4 * 65536);
        f32x4 aq[2] = {}, ak[2] = {}, av[2] = {};
        #pragma unroll 1
        for (int ks = 0; ks < 8; ++ks) {
            short8 a_h = lds_frag(aHi + aoff + ks * 32);
            short8 a_l = lds_frag(aLo + aoff + ks * 32);
            #pragma unroll
            for (int ti = 0; ti < 2; ++ti) {
                int off = ((w * 2 + ti) * 8 + ks) * 64 + l;
                V8 qh, ql, kh, kl, vh, vl;
                qh.u = Hq[off]; ql.u = Lq[off];
                kh.u = Hk[off]; kl.u = Lk[off];
                vh.u = Hv[off]; vl.u = Lv[off];
                aq[ti] = __builtin_amdgcn_mfma_f32_16x16x32_bf16(a_h, qh.s, aq[ti], 0, 0, 0);
                aq[ti] = __builtin_amdgcn_mfma_f32_16x16x32_bf16(a_l, qh.s, aq[ti], 0, 0, 0);
                aq[ti] = __builtin_amdgcn_mfma_f32_16x16x32_bf16(a_h, ql.s, aq[ti], 0, 0, 0);
                ak[ti] = __builtin_amdgcn_mfma_f32_16x16x32_bf16(a_h, kh.s, ak[ti], 0, 0, 0);
                ak[ti] = __builtin_amdgcn_mfma_f32_16x16x32_bf16(a_l, kh.s, ak[ti], 0, 0, 0);
                ak[ti] = __builtin_amdgcn_mfma_f32_16x16x32_bf16(a_h, kl.s, ak[ti], 0, 0, 0);
                av[ti] = __builtin_amdgcn_mfma_f32_16x16x32_bf16(a_h, vh.s, av[ti], 0, 0, 0);
                av[ti] = __builtin_amdgcn_mfma_f32_16x16x32_bf16(a_l, vh.s, av[ti], 0, 0, 0);
                av[ti] = __builtin_amdgcn_mfma_f32_16x16x32_bf16(a_h, vl.s, av[ti], 0, 0, 0);
            }
        }
        #pragma unroll
        for (int ti = 0; ti < 2; ++ti) {
            int n0 = (w * 2 + ti) * 16 + lr;
            float bq = Bq[n0], bk = Bk[n0], bv = Bv[n0];
            #pragma unroll
            for (int r = 0; r < 4; ++r) {
                int go = (r0 + quad * 4 + r) * 256 + n0;
                Q[go] = aq[ti][r] + bq;
                K[go] = ak[ti][r] + bk;
                V[go] = av[ti][r] + bv;
            }
        }
    }
}

// ---------------------------------------------------------------------------
// MFMA attention: 256 blocks = (b,h), 512 thr = 8 waves; wave w = row-tile w.
// QK^T: one 16x16x32 MFMA per (rt,ct) with Q/K frags direct from global.
// Mask bias pre-staged in ps (bf16); softmax in-register; P->ps bf16 (rows
// are wave-private); PV: A=P frags, B=V^T frags from LDS.
// ---------------------------------------------------------------------------
__global__ __launch_bounds__(512) void k_attn_mfma(
    const float* __restrict__ Q, const float* __restrict__ K,
    const float* __restrict__ V, const float* __restrict__ conn,
    float* __restrict__ AO) {
    int bh = blockIdx.x;
    int b = bh >> 3, h = bh & 7;
    int t = threadIdx.x;
    int lane = t & 63, w = t >> 6;
    __shared__ __align__(16) ushort vT[32 * 136];
    __shared__ __align__(16) ushort ps[128 * 136];
    // stage mask bias into ps: (conn-1)*1e9 as bf16 (0 or ~-1e9)
    for (int idx = t; idx < 16384; idx += 512) {
        float c = conn[h * 16384 + idx];
        ps[(idx >> 7) * 136 + (idx & 127)] = bf16bits((c - 1.f) * 1e9f);
    }
    // stage V transposed: vT[d][key]
    for (int idx = t; idx < 4096; idx += 512) {
        int key = idx & 127, d = idx >> 7;
        vT[d * 136 + key] = bf16bits(V[b * 32768 + key * 256 + h * 32 + d]);
    }
    __syncthreads();
    int lr = lane & 15, quad = lane >> 4;
    // A-frag: Q rows w*16+lr, k = quad*8+j over d_k=32
    const float* qp = Q + b * 32768 + (w * 16 + lr) * 256 + h * 32 + quad * 8;
    float4 q0 = *(const float4*)qp, q1 = *(const float4*)(qp + 4);
    V8 af;
    af.u.x = pk(q0.x, q0.y); af.u.y = pk(q0.z, q0.w);
    af.u.z = pk(q1.x, q1.y); af.u.w = pk(q1.z, q1.w);
    f32x4 s[8];
    #pragma unroll
    for (int ct = 0; ct < 8; ++ct) {
        const float* kp = K + b * 32768 + (ct * 16 + lr) * 256 + h * 32 + quad * 8;
        float4 k0 = *(const float4*)kp, k1 = *(const float4*)(kp + 4);
        V8 bf_;
        bf_.u.x = pk(k0.x, k0.y); bf_.u.y = pk(k0.z, k0.w);
        bf_.u.z = pk(k1.x, k1.y); bf_.u.w = pk(k1.z, k1.w);
        f32x4 z = {0.f, 0.f, 0.f, 0.f};
        s[ct] = __builtin_amdgcn_mfma_f32_16x16x32_bf16(af.s, bf_.s, z, 0, 0, 0);
    }
    const float scale = 0.17677669529663687f;  // 32^-0.5
    #pragma unroll
    for (int r = 0; r < 4; ++r) {
        int row = w * 16 + quad * 4 + r;
        float sv[8];
        float mx = -3.0e38f;
        #pragma unroll
        for (int ct = 0; ct < 8; ++ct) {
            float bias = bits_to_f(ps[row * 136 + ct * 16 + lr]);
            sv[ct] = s[ct][r] * scale + bias;
            mx = fmaxf(mx, sv[ct]);
        }
        mx = fmaxf(mx, __shfl_xor(mx, 1));
        mx = fmaxf(mx, __shfl_xor(mx, 2));
        mx = fmaxf(mx, __shfl_xor(mx, 4));
        mx = fmaxf(mx, __shfl_xor(mx, 8));
        float sum = 0.f;
        #pragma unroll
        for (int ct = 0; ct < 8; ++ct) {
            sv[ct] = __expf(sv[ct] - mx);
            sum += sv[ct];
        }
        sum += __shfl_xor(sum, 1);
        sum += __shfl_xor(sum, 2);
        sum += __shfl_xor(sum, 4);
        sum += __shfl_xor(sum, 8);
        float iv = 1.f / sum;
        #pragma unroll
        for (int ct = 0; ct < 8; ++ct)
            ps[row * 136 + ct * 16 + lr] = bf16bits(sv[ct] * iv);
    }
    __syncthreads();  // cheap safety; rows are wave-private
    // PV: O[16 x 32] per wave; A = P frags (contiguous keys), B = vT frags
    f32x4 o0 = {}, o1 = {};
    #pragma unroll
    for (int kk = 0; kk < 4; ++kk) {
        short8 pa = lds_frag(ps + (w * 16 + lr) * 136 + kk * 32 + quad * 8);
        short8 v0 = lds_frag(vT + lr * 136 + kk * 32 + quad * 8);
        short8 v1 = lds_frag(vT + (16 + lr) * 136 + kk * 32 + quad * 8);
        o0 = __builtin_amdgcn_mfma_f32_16x16x32_bf16(pa, v0, o0, 0, 0, 0);
        o1 = __builtin_amdgcn_mfma_f32_16x16x32_bf16(pa, v1, o1, 0, 0, 0);
    }
    #pragma unroll
    for (int r = 0; r < 4; ++r) {
        int row = w * 16 + quad * 4 + r;
        float* op = AO + b * 32768 + row * 256 + h * 32;
        op[lr] = o0[r];
        op[16 + lr] = o1[r];
    }
}

// ---------------------------------------------------------------------------
// Out-proj MFMA GEMM: Y = X @ W + b. 256 blocks x 16 rows, 512 threads.
// ---------------------------------------------------------------------------
template <int ACT>
__global__ __launch_bounds__(512) void k_gemm16(
    const float* __restrict__ X, const ushort* __restrict__ Whi,
    const ushort* __restrict__ Wlo, const float* __restrict__ bias,
    float* __restrict__ Y) {
    __shared__ __align__(16) ushort xhi[16 * 264], xlo[16 * 264];
    int t = threadIdx.x;
    int r0 = blockIdx.x * 16;
    #pragma unroll
    for (int ii = 0; ii < 2; ++ii) {
        int f4 = ii * 512 + t;
        int row = f4 >> 6, c = (f4 & 63) * 4;
        float4 xv = *(const float4*)(X + (r0 + row) * 256 + c);
        ushort h[4], l[4];
        split_bf16(xv.x, h[0], l[0]); split_bf16(xv.y, h[1], l[1]);
        split_bf16(xv.z, h[2], l[2]); split_bf16(xv.w, h[3], l[3]);
        uint2 ph = { (uint)h[0] | ((uint)h[1] << 16), (uint)h[2] | ((uint)h[3] << 16) };
        uint2 pl = { (uint)l[0] | ((uint)l[1] << 16), (uint)l[2] | ((uint)l[3] << 16) };
        *(uint2*)(xhi + row * 264 + c) = ph;
        *(uint2*)(xlo + row * 264 + c) = pl;
    }
    __syncthreads();
    int l = t & 63, w = t >> 6;
    int lr = l & 15, quad = l >> 4;
    const ushort* ah = xhi + lr * 264 + quad * 8;
    const ushort* al = xlo + lr * 264 + quad * 8;
    const uint4* H4 = (const uint4*)Whi;
    const uint4* L4 = (const uint4*)Wlo;
    f32x4 acc[2] = {};
    #pragma unroll 2
    for (int ks = 0; ks < 8; ++ks) {
        short8 a_h = lds_frag(ah + ks * 32);
        short8 a_l = lds_frag(al + ks * 32);
        #pragma unroll
        for (int ti = 0; ti < 2; ++ti) {
            int off = ((w * 2 + ti) * 8 + ks) * 64 + l;
            V8 bh, bl; bh.u = H4[off]; bl.u = L4[off];
            acc[ti] = __builtin_amdgcn_mfma_f32_16x16x32_bf16(a_h, bh.s, acc[ti], 0, 0, 0);
            acc[ti] = __builtin_amdgcn_mfma_f32_16x16x32_bf16(a_l, bh.s, acc[ti], 0, 0, 0);
            acc[ti] = __builtin_amdgcn_mfma_f32_16x16x32_bf16(a_h, bl.s, acc[ti], 0, 0, 0);
        }
    }
    #pragma unroll
    for (int ti = 0; ti < 2; ++ti) {
        int n0 = (w * 2 + ti) * 16 + lr;
        float bs = bias[n0];
        #pragma unroll
        for (int r = 0; r < 4; ++r) {
            float o = acc[ti][r] + bs;
            if (ACT) o = gelu_f(o);
            Y[(r0 + quad * 4 + r) * 256 + n0] = o;
        }
    }
}

// ---------------------------------------------------------------------------
extern "C" void kernel_launch(void* const* d_in, const int* in_sizes, int n_in,
                              void* d_out, int out_size, void* d_ws, size_t ws_size,
                              hipStream_t stream) {
    const float* x        = (const float*)d_in[0];
    const float* gumbel_u = (const float*)d_in[1];
    const float* memory_w = (const float*)d_in[2];
    const float* fc_out_w = (const float*)d_in[3];
    const float* fc_out_b = (const float*)d_in[4];
    const float* fc_cat_w = (const float*)d_in[5];
    const float* fc_cat_b = (const float*)d_in[6];
    const float* wq       = (const float*)d_in[7];
    const float* bq       = (const float*)d_in[8];
    const float* wk       = (const float*)d_in[9];
    const float* bk       = (const float*)d_in[10];
    const float* wv_      = (const float*)d_in[11];
    const float* bv_      = (const float*)d_in[12];
    const float* out_w    = (const float*)d_in[13];
    const float* out_b    = (const float*)d_in[14];
    const float* mlp_w1   = (const float*)d_in[15];
    const float* mlp_b1   = (const float*)d_in[16];
    const float* mlp_w2   = (const float*)d_in[17];
    const float* mlp_b2   = (const float*)d_in[18];

    float* ws   = (float*)d_ws;
    float* A    = ws;                 //  262144 floats
    float* Bm   = ws + 262144;        //  262144
    float* conn = ws + 524288;        //  131072
    float* q    = ws + 655360;        // 1048576
    float* k    = ws + 1703936;       // 1048576
    float* v    = ws + 2752512;       // 1048576
    float* ao   = ws + 3801088;       // 1048576
    ushort* wf_hi = (ushort*)(ws + 4849664);   // 6*65536 ushorts
    ushort* wf_lo = wf_hi + 6 * 65536;
    float* out  = (float*)d_out;

    // weight order: 0=mlp_w1 1=mlp_w2 2=wq 3=wk 4=wv 5=out_w
    k_wprep<<<dim3(96), dim3(256), 0, stream>>>(mlp_w1, mlp_w2, wq, wk, wv_, out_w,
                                                wf_hi, wf_lo);
    k_featproj<<<dim3(256), dim3(256), 0, stream>>>(memory_w, fc_out_w, A, Bm);
    k_conn<<<dim3(512), dim3(256), 0, stream>>>(A, Bm, fc_out_b, fc_cat_w, fc_cat_b,
                                                gumbel_u, conn);
    k_fused5<<<dim3(256), dim3(512), 0, stream>>>(x, wf_hi, wf_lo, mlp_b1, mlp_b2,
                                                  bq, bk, bv_, q, k, v);
    k_attn_mfma<<<dim3(256), dim3(512), 0, stream>>>(q, k, v, conn, ao);
    k_gemm16<0><<<dim3(256), dim3(512), 0, stream>>>(ao, wf_hi + 5 * 65536,
                                                     wf_lo + 5 * 65536, out_b, out);
}

// Round 5
// 169.976 us; speedup vs baseline: 1.9079x; 1.1158x over previous
//
#include <hip/hip_runtime.h>
#include <hip/hip_bf16.h>
#include <math.h>

// Problem constants: H=8, d_model=256, N=128, d_k=32, B=32, rows=4096

typedef short short8 __attribute__((ext_vector_type(8)));
typedef float f32x4 __attribute__((ext_vector_type(4)));

union V8 { uint4 u; short8 s; };

__device__ __forceinline__ float gelu_f(float x) {
    float inner = 0.7978845608028654f * (x + 0.044715f * x * x * x);
    return 0.5f * x * (1.0f + tanhf(inner));
}

__device__ __forceinline__ void split_bf16(float x, ushort& h, ushort& l) {
    __hip_bfloat16 bh = __float2bfloat16(x);          // RN
    float hf = __bfloat162float(bh);
    __hip_bfloat16 bl = __float2bfloat16(x - hf);
    h = __builtin_bit_cast(ushort, bh);
    l = __builtin_bit_cast(ushort, bl);
}

__device__ __forceinline__ ushort bf16bits(float x) {
    return __builtin_bit_cast(ushort, __float2bfloat16(x));
}
__device__ __forceinline__ float bits_to_f(ushort v) {
    return __builtin_bit_cast(float, ((uint)v) << 16);
}
__device__ __forceinline__ uint pk(float a, float b) {
    return (uint)bf16bits(a) | ((uint)bf16bits(b) << 16);
}
__device__ __forceinline__ short8 lds_frag(const ushort* p) {
    V8 v; v.u = *(const uint4*)p; return v.s;
}

// ---------------------------------------------------------------------------
// Weight prep: 8 matrices of W[256k x 256n] fp32 -> fragment-ordered bf16
// hi/lo. B-frag for (coltile tg, kstep ks) = uint4 at [(tg*8+ks)*64 + lane].
// Mats: 0=mlp_w1 1=mlp_w2 2=wq 3=wk 4=wv 5=out_w 6=fc_out_w[0:256] 7=[256:512]
// grid 128 = 8 mats x 16 col-tiles, 256 threads.
// ---------------------------------------------------------------------------
__global__ __launch_bounds__(256) void k_wprep(
    const float* __restrict__ w0, const float* __restrict__ w1,
    const float* __restrict__ w2, const float* __restrict__ w3,
    const float* __restrict__ w4, const float* __restrict__ w5,
    const float* __restrict__ w6, const float* __restrict__ w7,
    ushort* __restrict__ hi, ushort* __restrict__ lo) {
    int m = blockIdx.x >> 4, tn = blockIdx.x & 15;
    const float* W = m == 0 ? w0 : m == 1 ? w1 : m == 2 ? w2 : m == 3 ? w3 :
                     m == 4 ? w4 : m == 5 ? w5 : m == 6 ? w6 : w7;
    ushort* Hm = hi + m * 65536;
    ushort* Lm = lo + m * 65536;
    int t = threadIdx.x;
    int n = tn * 16 + (t & 15);
    int k0 = (t >> 4) * 16;
    ushort hb[16], lb[16];
    #pragma unroll
    for (int kk = 0; kk < 16; ++kk)
        split_bf16(W[(k0 + kk) * 256 + n], hb[kk], lb[kk]);
    int ks = k0 >> 5;
    int q0 = (k0 >> 3) & 3;
    #pragma unroll
    for (int rb = 0; rb < 2; ++rb) {
        int lane = ((q0 + rb) << 4) | (t & 15);
        int idx = ((tn * 8 + ks) * 64 + lane) * 8;
        const ushort* hp = hb + rb * 8;
        const ushort* lp = lb + rb * 8;
        uint4 ph = { (uint)hp[0] | ((uint)hp[1] << 16), (uint)hp[2] | ((uint)hp[3] << 16),
                     (uint)hp[4] | ((uint)hp[5] << 16), (uint)hp[6] | ((uint)hp[7] << 16) };
        uint4 pl = { (uint)lp[0] | ((uint)lp[1] << 16), (uint)lp[2] | ((uint)lp[3] << 16),
                     (uint)lp[4] | ((uint)lp[5] << 16), (uint)lp[6] | ((uint)lp[7] << 16) };
        *(uint4*)(Hm + idx) = ph;
        *(uint4*)(Lm + idx) = pl;
    }
}

// ---------------------------------------------------------------------------
// featproj (MFMA): A/Bm[1024,256] = feats[1024,256] @ {W_top|W_bot}.
// feats row r=(h*128+n): memory_w[n*2048 + h*256 + :].
// grid (64 rowtiles, 8): y = colquad(0..3)*2 + matsel; 256 thr = 4 waves,
// wave w -> coltile tg = cq*4 + w.
// ---------------------------------------------------------------------------
__global__ __launch_bounds__(256) void k_featproj(
    const float* __restrict__ memory_w,
    const ushort* __restrict__ Whi, const ushort* __restrict__ Wlo,
    float* __restrict__ A, float* __restrict__ Bm) {
    __shared__ __align__(16) ushort xhi[16 * 264], xlo[16 * 264];
    int t = threadIdx.x;
    int rt = blockIdx.x;
    int msel = blockIdx.y & 1, cq = blockIdx.y >> 1;
    #pragma unroll
    for (int ii = 0; ii < 4; ++ii) {
        int f4 = ii * 256 + t;
        int rr = f4 >> 6, c = (f4 & 63) * 4;
        int r = rt * 16 + rr;
        int h = r >> 7, n = r & 127;
        float4 xv = *(const float4*)(memory_w + n * 2048 + h * 256 + c);
        ushort hh[4], ll[4];
        split_bf16(xv.x, hh[0], ll[0]); split_bf16(xv.y, hh[1], ll[1]);
        split_bf16(xv.z, hh[2], ll[2]); split_bf16(xv.w, hh[3], ll[3]);
        uint2 ph = { (uint)hh[0] | ((uint)hh[1] << 16), (uint)hh[2] | ((uint)hh[3] << 16) };
        uint2 pl = { (uint)ll[0] | ((uint)ll[1] << 16), (uint)ll[2] | ((uint)ll[3] << 16) };
        *(uint2*)(xhi + rr * 264 + c) = ph;
        *(uint2*)(xlo + rr * 264 + c) = pl;
    }
    __syncthreads();
    int l = t & 63, w = t >> 6;
    int lr = l & 15, quad = l >> 4;
    int tg = cq * 4 + w;
    const uint4* H4 = (const uint4*)(Whi + (6 + msel) * 65536);
    const uint4* L4 = (const uint4*)(Wlo + (6 + msel) * 65536);
    const ushort* ah = xhi + lr * 264 + quad * 8;
    const ushort* al = xlo + lr * 264 + quad * 8;
    f32x4 acc = {};
    #pragma unroll 4
    for (int ks = 0; ks < 8; ++ks) {
        short8 a_h = lds_frag(ah + ks * 32);
        short8 a_l = lds_frag(al + ks * 32);
        int off = (tg * 8 + ks) * 64 + l;
        V8 bh, bl; bh.u = H4[off]; bl.u = L4[off];
        acc = __builtin_amdgcn_mfma_f32_16x16x32_bf16(a_h, bh.s, acc, 0, 0, 0);
        acc = __builtin_amdgcn_mfma_f32_16x16x32_bf16(a_l, bh.s, acc, 0, 0, 0);
        acc = __builtin_amdgcn_mfma_f32_16x16x32_bf16(a_h, bl.s, acc, 0, 0, 0);
    }
    float* O = msel ? Bm : A;
    int n0 = tg * 16 + lr;
    #pragma unroll
    for (int r = 0; r < 4; ++r)
        O[(rt * 16 + quad * 4 + r) * 256 + n0] = acc[r];
}

// ---------------------------------------------------------------------------
// conn: maskb[h,i,j] = bf16( conn ? 0 : -1e9 ) where conn = (l1+g1)>(l0+g0).
// grid 512 = (h, i-pair), 256 thr = (di) x (j). fc_cat_w read wave-uniform.
// ---------------------------------------------------------------------------
__global__ __launch_bounds__(256) void k_conn(
    const float* __restrict__ A, const float* __restrict__ Bm,
    const float* __restrict__ fc_out_b, const float* __restrict__ fc_cat_w,
    const float* __restrict__ fc_cat_b, const float* __restrict__ gumbel_u,
    ushort* __restrict__ maskb) {
    int blk = blockIdx.x;
    int h = blk >> 6, i0 = (blk & 63) * 2;
    int t = threadIdx.x;
    int j = t & 127, di = t >> 7;
    int i = i0 + di;
    __shared__ __align__(16) float sB[2 * 256];
    {
        float fb = fc_out_b[t];
        sB[t]       = Bm[(h * 128 + i0) * 256 + t] + fb;
        sB[256 + t] = Bm[(h * 128 + i0 + 1) * 256 + t] + fb;
    }
    __syncthreads();
    const float4* Arow4 = (const float4*)(A + (h * 128 + j) * 256);
    const float* sBr = sB + di * 256;
    float l0 = fc_cat_b[0], l1 = fc_cat_b[1];
    #pragma unroll 4
    for (int d4 = 0; d4 < 64; ++d4) {
        float4 av = Arow4[d4];
        int d = d4 * 4;
        float4 bv = *(const float4*)(sBr + d);
        // wave-uniform scalar loads of fc_cat_w pairs
        float4 cwA = *(const float4*)(fc_cat_w + d * 2);       // w0[d],w1[d],w0[d+1],w1[d+1]
        float4 cwB = *(const float4*)(fc_cat_w + d * 2 + 4);   // w0[d+2],w1[d+2],w0[d+3],w1[d+3]
        float h0 = fmaxf(av.x + bv.x, 0.f);
        float h1 = fmaxf(av.y + bv.y, 0.f);
        float h2 = fmaxf(av.z + bv.z, 0.f);
        float h3 = fmaxf(av.w + bv.w, 0.f);
        l0 += h0 * cwA.x + h1 * cwA.z + h2 * cwB.x + h3 * cwB.z;
        l1 += h0 * cwA.y + h1 * cwA.w + h2 * cwB.y + h3 * cwB.w;
    }
    int gb = ((h * 128 + i) * 128 + j) * 2;
    float u0 = gumbel_u[gb], u1 = gumbel_u[gb + 1];
    float g0 = -logf(-logf(u0 + 1e-10f) + 1e-10f);
    float g1 = -logf(-logf(u1 + 1e-10f) + 1e-10f);
    bool on = (l1 + g1) > (l0 + g0);
    maskb[(h * 128 + i) * 128 + j] = bf16bits(on ? 0.f : -1e9f);
}

// ---------------------------------------------------------------------------
// Col-split MFMA GEMM: Y[4096,256] = act(X @ W + b).
// grid (256 rowtiles, 2 colhalves), 256 thr = 4 waves; wave w -> 2 coltiles
// tg = ch*8 + w*2 + ti. ACT: 0 none, 1 gelu.
// ---------------------------------------------------------------------------
template <int ACT>
__global__ __launch_bounds__(256) void k_gemm16(
    const float* __restrict__ X, const ushort* __restrict__ Whi,
    const ushort* __restrict__ Wlo, const float* __restrict__ bias,
    float* __restrict__ Y) {
    __shared__ __align__(16) ushort xhi[16 * 264], xlo[16 * 264];
    int t = threadIdx.x;
    int r0 = blockIdx.x * 16;
    int ch = blockIdx.y;
    #pragma unroll
    for (int ii = 0; ii < 4; ++ii) {
        int f4 = ii * 256 + t;
        int row = f4 >> 6, c = (f4 & 63) * 4;
        float4 xv = *(const float4*)(X + (r0 + row) * 256 + c);
        ushort h[4], l[4];
        split_bf16(xv.x, h[0], l[0]); split_bf16(xv.y, h[1], l[1]);
        split_bf16(xv.z, h[2], l[2]); split_bf16(xv.w, h[3], l[3]);
        uint2 ph = { (uint)h[0] | ((uint)h[1] << 16), (uint)h[2] | ((uint)h[3] << 16) };
        uint2 pl = { (uint)l[0] | ((uint)l[1] << 16), (uint)l[2] | ((uint)l[3] << 16) };
        *(uint2*)(xhi + row * 264 + c) = ph;
        *(uint2*)(xlo + row * 264 + c) = pl;
    }
    __syncthreads();
    int l = t & 63, w = t >> 6;
    int lr = l & 15, quad = l >> 4;
    const ushort* ah = xhi + lr * 264 + quad * 8;
    const ushort* al = xlo + lr * 264 + quad * 8;
    const uint4* H4 = (const uint4*)Whi;
    const uint4* L4 = (const uint4*)Wlo;
    f32x4 acc[2] = {};
    #pragma unroll 2
    for (int ks = 0; ks < 8; ++ks) {
        short8 a_h = lds_frag(ah + ks * 32);
        short8 a_l = lds_frag(al + ks * 32);
        #pragma unroll
        for (int ti = 0; ti < 2; ++ti) {
            int tg = ch * 8 + w * 2 + ti;
            int off = (tg * 8 + ks) * 64 + l;
            V8 bh, bl; bh.u = H4[off]; bl.u = L4[off];
            acc[ti] = __builtin_amdgcn_mfma_f32_16x16x32_bf16(a_h, bh.s, acc[ti], 0, 0, 0);
            acc[ti] = __builtin_amdgcn_mfma_f32_16x16x32_bf16(a_l, bh.s, acc[ti], 0, 0, 0);
            acc[ti] = __builtin_amdgcn_mfma_f32_16x16x32_bf16(a_h, bl.s, acc[ti], 0, 0, 0);
        }
    }
    #pragma unroll
    for (int ti = 0; ti < 2; ++ti) {
        int n0 = (ch * 8 + w * 2 + ti) * 16 + lr;
        float bs = bias[n0];
        #pragma unroll
        for (int r = 0; r < 4; ++r) {
            float o = acc[ti][r] + bs;
            if (ACT) o = gelu_f(o);
            Y[(r0 + quad * 4 + r) * 256 + n0] = o;
        }
    }
}

// ---------------------------------------------------------------------------
// qkv: grid (256 rowtiles, 6): y -> out = y>>1 (0=Q 1=K 2=V), ch = y&1.
// Weight mat index = 2 + (y>>1).
// ---------------------------------------------------------------------------
__global__ __launch_bounds__(256) void k_qkv(
    const float* __restrict__ X, const ushort* __restrict__ Whi,
    const ushort* __restrict__ Wlo,
    const float* __restrict__ Bq, const float* __restrict__ Bk,
    const float* __restrict__ Bv,
    float* __restrict__ Q, float* __restrict__ K, float* __restrict__ V) {
    __shared__ __align__(16) ushort xhi[16 * 264], xlo[16 * 264];
    int t = threadIdx.x;
    int r0 = blockIdx.x * 16;
    int osel = blockIdx.y >> 1, ch = blockIdx.y & 1;
    #pragma unroll
    for (int ii = 0; ii < 4; ++ii) {
        int f4 = ii * 256 + t;
        int row = f4 >> 6, c = (f4 & 63) * 4;
        float4 xv = *(const float4*)(X + (r0 + row) * 256 + c);
        ushort h[4], l[4];
        split_bf16(xv.x, h[0], l[0]); split_bf16(xv.y, h[1], l[1]);
        split_bf16(xv.z, h[2], l[2]); split_bf16(xv.w, h[3], l[3]);
        uint2 ph = { (uint)h[0] | ((uint)h[1] << 16), (uint)h[2] | ((uint)h[3] << 16) };
        uint2 pl = { (uint)l[0] | ((uint)l[1] << 16), (uint)l[2] | ((uint)l[3] << 16) };
        *(uint2*)(xhi + row * 264 + c) = ph;
        *(uint2*)(xlo + row * 264 + c) = pl;
    }
    __syncthreads();
    int l = t & 63, w = t >> 6;
    int lr = l & 15, quad = l >> 4;
    const ushort* ah = xhi + lr * 264 + quad * 8;
    const ushort* al = xlo + lr * 264 + quad * 8;
    const uint4* H4 = (const uint4*)(Whi + (2 + osel) * 65536);
    const uint4* L4 = (const uint4*)(Wlo + (2 + osel) * 65536);
    f32x4 acc[2] = {};
    #pragma unroll 2
    for (int ks = 0; ks < 8; ++ks) {
        short8 a_h = lds_frag(ah + ks * 32);
        short8 a_l = lds_frag(al + ks * 32);
        #pragma unroll
        for (int ti = 0; ti < 2; ++ti) {
            int tg = ch * 8 + w * 2 + ti;
            int off = (tg * 8 + ks) * 64 + l;
            V8 bh, bl; bh.u = H4[off]; bl.u = L4[off];
            acc[ti] = __builtin_amdgcn_mfma_f32_16x16x32_bf16(a_h, bh.s, acc[ti], 0, 0, 0);
            acc[ti] = __builtin_amdgcn_mfma_f32_16x16x32_bf16(a_l, bh.s, acc[ti], 0, 0, 0);
            acc[ti] = __builtin_amdgcn_mfma_f32_16x16x32_bf16(a_h, bl.s, acc[ti], 0, 0, 0);
        }
    }
    const float* Bp = osel == 0 ? Bq : osel == 1 ? Bk : Bv;
    float* O = osel == 0 ? Q : osel == 1 ? K : V;
    #pragma unroll
    for (int ti = 0; ti < 2; ++ti) {
        int n0 = (ch * 8 + w * 2 + ti) * 16 + lr;
        float bs = Bp[n0];
        #pragma unroll
        for (int r = 0; r < 4; ++r)
            O[(r0 + quad * 4 + r) * 256 + n0] = acc[ti][r] + bs;
    }
}

// ---------------------------------------------------------------------------
// MFMA attention: 256 blocks = (b,h), 512 thr = 8 waves; wave w = row-tile w.
// Mask bias read directly from global bf16 (L2-hot). V staged transposed.
// ---------------------------------------------------------------------------
__global__ __launch_bounds__(512) void k_attn_mfma(
    const float* __restrict__ Q, const float* __restrict__ K,
    const float* __restrict__ V, const ushort* __restrict__ maskb,
    float* __restrict__ AO) {
    int bh = blockIdx.x;
    int b = bh >> 3, h = bh & 7;
    int t = threadIdx.x;
    int lane = t & 63, w = t >> 6;
    __shared__ __align__(16) ushort vT[32 * 136];
    __shared__ __align__(16) ushort ps[128 * 136];
    // stage V transposed, coalesced reads
    #pragma unroll
    for (int it = 0; it < 2; ++it) {
        int f4 = it * 512 + t;
        int key = f4 >> 3, dq = (f4 & 7) * 4;
        float4 vv = *(const float4*)(V + b * 32768 + key * 256 + h * 32 + dq);
        vT[(dq + 0) * 136 + key] = bf16bits(vv.x);
        vT[(dq + 1) * 136 + key] = bf16bits(vv.y);
        vT[(dq + 2) * 136 + key] = bf16bits(vv.z);
        vT[(dq + 3) * 136 + key] = bf16bits(vv.w);
    }
    __syncthreads();
    int lr = lane & 15, quad = lane >> 4;
    // QK^T
    const float* qp = Q + b * 32768 + (w * 16 + lr) * 256 + h * 32 + quad * 8;
    float4 q0 = *(const float4*)qp, q1 = *(const float4*)(qp + 4);
    V8 af;
    af.u.x = pk(q0.x, q0.y); af.u.y = pk(q0.z, q0.w);
    af.u.z = pk(q1.x, q1.y); af.u.w = pk(q1.z, q1.w);
    f32x4 s[8];
    #pragma unroll
    for (int ct = 0; ct < 8; ++ct) {
        const float* kp = K + b * 32768 + (ct * 16 + lr) * 256 + h * 32 + quad * 8;
        float4 k0 = *(const float4*)kp, k1 = *(const float4*)(kp + 4);
        V8 bf_;
        bf_.u.x = pk(k0.x, k0.y); bf_.u.y = pk(k0.z, k0.w);
        bf_.u.z = pk(k1.x, k1.y); bf_.u.w = pk(k1.z, k1.w);
        f32x4 z = {0.f, 0.f, 0.f, 0.f};
        s[ct] = __builtin_amdgcn_mfma_f32_16x16x32_bf16(af.s, bf_.s, z, 0, 0, 0);
    }
    const float scale = 0.17677669529663687f;  // 32^-0.5
    const ushort* mrow = maskb + h * 16384;
    #pragma unroll
    for (int r = 0; r < 4; ++r) {
        int row = w * 16 + quad * 4 + r;
        float sv[8];
        float mx = -3.0e38f;
        #pragma unroll
        for (int ct = 0; ct < 8; ++ct) {
            float bias = bits_to_f(mrow[row * 128 + ct * 16 + lr]);
            sv[ct] = s[ct][r] * scale + bias;
            mx = fmaxf(mx, sv[ct]);
        }
        mx = fmaxf(mx, __shfl_xor(mx, 1));
        mx = fmaxf(mx, __shfl_xor(mx, 2));
        mx = fmaxf(mx, __shfl_xor(mx, 4));
        mx = fmaxf(mx, __shfl_xor(mx, 8));
        float sum = 0.f;
        #pragma unroll
        for (int ct = 0; ct < 8; ++ct) {
            sv[ct] = __expf(sv[ct] - mx);
            sum += sv[ct];
        }
        sum += __shfl_xor(sum, 1);
        sum += __shfl_xor(sum, 2);
        sum += __shfl_xor(sum, 4);
        sum += __shfl_xor(sum, 8);
        float iv = 1.f / sum;
        #pragma unroll
        for (int ct = 0; ct < 8; ++ct)
            ps[row * 136 + ct * 16 + lr] = bf16bits(sv[ct] * iv);
    }
    // PV (rows are wave-private; no barrier needed)
    f32x4 o0 = {}, o1 = {};
    #pragma unroll
    for (int kk = 0; kk < 4; ++kk) {
        short8 pa = lds_frag(ps + (w * 16 + lr) * 136 + kk * 32 + quad * 8);
        short8 v0 = lds_frag(vT + lr * 136 + kk * 32 + quad * 8);
        short8 v1 = lds_frag(vT + (16 + lr) * 136 + kk * 32 + quad * 8);
        o0 = __builtin_amdgcn_mfma_f32_16x16x32_bf16(pa, v0, o0, 0, 0, 0);
        o1 = __builtin_amdgcn_mfma_f32_16x16x32_bf16(pa, v1, o1, 0, 0, 0);
    }
    #pragma unroll
    for (int r = 0; r < 4; ++r) {
        int row = w * 16 + quad * 4 + r;
        float* op = AO + b * 32768 + row * 256 + h * 32;
        op[lr] = o0[r];
        op[16 + lr] = o1[r];
    }
}

// ---------------------------------------------------------------------------
extern "C" void kernel_launch(void* const* d_in, const int* in_sizes, int n_in,
                              void* d_out, int out_size, void* d_ws, size_t ws_size,
                              hipStream_t stream) {
    const float* x        = (const float*)d_in[0];
    const float* gumbel_u = (const float*)d_in[1];
    const float* memory_w = (const float*)d_in[2];
    const float* fc_out_w = (const float*)d_in[3];
    const float* fc_out_b = (const float*)d_in[4];
    const float* fc_cat_w = (const float*)d_in[5];
    const float* fc_cat_b = (const float*)d_in[6];
    const float* wq       = (const float*)d_in[7];
    const float* bq       = (const float*)d_in[8];
    const float* wk       = (const float*)d_in[9];
    const float* bk       = (const float*)d_in[10];
    const float* wv_      = (const float*)d_in[11];
    const float* bv_      = (const float*)d_in[12];
    const float* out_w    = (const float*)d_in[13];
    const float* out_b    = (const float*)d_in[14];
    const float* mlp_w1   = (const float*)d_in[15];
    const float* mlp_b1   = (const float*)d_in[16];
    const float* mlp_w2   = (const float*)d_in[17];
    const float* mlp_b2   = (const float*)d_in[18];

    float* ws    = (float*)d_ws;
    float* A     = ws;                  //  262144 f
    float* Bm    = ws + 262144;         //  262144 f
    ushort* mask = (ushort*)(ws + 524288);   // 131072 ushort (65536 f)
    float* hbuf  = ws + 589824;         // 1048576 f
    float* xm    = ws + 1638400;        // 1048576 f
    float* q     = ws + 2686976;        // 1048576 f
    float* k     = ws + 3735552;        // 1048576 f
    float* v     = ws + 4784128;        // 1048576 f
    float* ao    = ws + 5832704;        // 1048576 f
    ushort* wf_hi = (ushort*)(ws + 6881280);  // 8*65536 ushort (262144 f)
    ushort* wf_lo = wf_hi + 8 * 65536;
    float* out   = (float*)d_out;

    k_wprep<<<dim3(128), dim3(256), 0, stream>>>(
        mlp_w1, mlp_w2, wq, wk, wv_, out_w, fc_out_w, fc_out_w + 65536,
        wf_hi, wf_lo);
    k_featproj<<<dim3(64, 8), dim3(256), 0, stream>>>(memory_w, wf_hi, wf_lo, A, Bm);
    k_conn<<<dim3(512), dim3(256), 0, stream>>>(A, Bm, fc_out_b, fc_cat_w, fc_cat_b,
                                                gumbel_u, mask);
    k_gemm16<1><<<dim3(256, 2), dim3(256), 0, stream>>>(x, wf_hi + 0 * 65536,
                                                        wf_lo + 0 * 65536, mlp_b1, hbuf);
    k_gemm16<0><<<dim3(256, 2), dim3(256), 0, stream>>>(hbuf, wf_hi + 1 * 65536,
                                                        wf_lo + 1 * 65536, mlp_b2, xm);
    k_qkv<<<dim3(256, 6), dim3(256), 0, stream>>>(xm, wf_hi, wf_lo, bq, bk, bv_, q, k, v);
    k_attn_mfma<<<dim3(256), dim3(512), 0, stream>>>(q, k, v, mask, ao);
    k_gemm16<0><<<dim3(256, 2), dim3(256), 0, stream>>>(ao, wf_hi + 5 * 65536,
                                                        wf_lo + 5 * 65536, out_b, out);
}

// Round 6
// 161.423 us; speedup vs baseline: 2.0090x; 1.0530x over previous
//
#include <hip/hip_runtime.h>
#include <hip/hip_bf16.h>
#include <math.h>

// Problem constants: H=8, d_model=256, N=128, d_k=32, B=32, rows=4096

typedef short short8 __attribute__((ext_vector_type(8)));
typedef float f32x4 __attribute__((ext_vector_type(4)));

union V8 { uint4 u; short8 s; };

__device__ __forceinline__ float gelu_f(float x) {
    float inner = 0.7978845608028654f * (x + 0.044715f * x * x * x);
    return 0.5f * x * (1.0f + tanhf(inner));
}

__device__ __forceinline__ void split_bf16(float x, ushort& h, ushort& l) {
    __hip_bfloat16 bh = __float2bfloat16(x);          // RN
    float hf = __bfloat162float(bh);
    __hip_bfloat16 bl = __float2bfloat16(x - hf);
    h = __builtin_bit_cast(ushort, bh);
    l = __builtin_bit_cast(ushort, bl);
}

__device__ __forceinline__ ushort bf16bits(float x) {
    return __builtin_bit_cast(ushort, __float2bfloat16(x));
}
__device__ __forceinline__ float bits_to_f(ushort v) {
    return __builtin_bit_cast(float, ((uint)v) << 16);
}
__device__ __forceinline__ uint pk(float a, float b) {
    return (uint)bf16bits(a) | ((uint)bf16bits(b) << 16);
}
__device__ __forceinline__ short8 lds_frag(const ushort* p) {
    V8 v; v.u = *(const uint4*)p; return v.s;
}

// ---------------------------------------------------------------------------
// Weight prep v2 (coalesced): W[256k x 256n] fp32 -> fragment-ordered bf16
// hi/lo. Frag layout: elem (k,n) -> m*65536 + ((tg*8+ks)*64 + lane)*8 + j
// with tg=n>>4, lr=n&15, ks=k>>5, quad=(k>>3)&3, j=k&7, lane=quad*16+lr.
// grid 128 = mat(8) x ks(8) x nhalf(2); 256 threads. Stage 32k x 128n in LDS.
// ---------------------------------------------------------------------------
__global__ __launch_bounds__(256) void k_wprep(
    const float* __restrict__ w0, const float* __restrict__ w1,
    const float* __restrict__ w2, const float* __restrict__ w3,
    const float* __restrict__ w4, const float* __restrict__ w5,
    const float* __restrict__ w6, const float* __restrict__ w7,
    ushort* __restrict__ hi, ushort* __restrict__ lo) {
    int bx = blockIdx.x;
    int m = bx >> 4, ks = (bx >> 1) & 7, nh = bx & 1;
    const float* W = m == 0 ? w0 : m == 1 ? w1 : m == 2 ? w2 : m == 3 ? w3 :
                     m == 4 ? w4 : m == 5 ? w5 : m == 6 ? w6 : w7;
    ushort* Hm = hi + m * 65536;
    ushort* Lm = lo + m * 65536;
    __shared__ __align__(16) float xs[32 * 132];
    int t = threadIdx.x;
    #pragma unroll
    for (int p = 0; p < 4; ++p) {
        int idx = p * 256 + t;
        int row = idx >> 5, c4 = (idx & 31) * 4;
        *(float4*)(xs + row * 132 + c4) =
            *(const float4*)(W + (ks * 32 + row) * 256 + nh * 128 + c4);
    }
    __syncthreads();
    int lane = t & 63, lr = lane & 15, quad = lane >> 4;
    #pragma unroll
    for (int it = 0; it < 2; ++it) {
        int tgl = (t >> 6) + 4 * it;
        int tg = nh * 8 + tgl;
        int nl = tgl * 16 + lr;
        ushort hb[8], lb[8];
        #pragma unroll
        for (int j = 0; j < 8; ++j)
            split_bf16(xs[(quad * 8 + j) * 132 + nl], hb[j], lb[j]);
        uint4 ph = { (uint)hb[0] | ((uint)hb[1] << 16), (uint)hb[2] | ((uint)hb[3] << 16),
                     (uint)hb[4] | ((uint)hb[5] << 16), (uint)hb[6] | ((uint)hb[7] << 16) };
        uint4 pl = { (uint)lb[0] | ((uint)lb[1] << 16), (uint)lb[2] | ((uint)lb[3] << 16),
                     (uint)lb[4] | ((uint)lb[5] << 16), (uint)lb[6] | ((uint)lb[7] << 16) };
        int idx = ((tg * 8 + ks) * 64 + lane) * 8;
        *(uint4*)(Hm + idx) = ph;
        *(uint4*)(Lm + idx) = pl;
    }
}

// ---------------------------------------------------------------------------
// featproj (MFMA): A/Bm[1024,256] = feats @ {W_top|W_bot}.
// grid (64 rowtiles, 8): y = colquad*2 + matsel; 256 thr, wave w -> tg=cq*4+w.
// ---------------------------------------------------------------------------
__global__ __launch_bounds__(256) void k_featproj(
    const float* __restrict__ memory_w,
    const ushort* __restrict__ Whi, const ushort* __restrict__ Wlo,
    float* __restrict__ A, float* __restrict__ Bm) {
    __shared__ __align__(16) ushort xhi[16 * 264], xlo[16 * 264];
    int t = threadIdx.x;
    int rt = blockIdx.x;
    int msel = blockIdx.y & 1, cq = blockIdx.y >> 1;
    #pragma unroll
    for (int ii = 0; ii < 4; ++ii) {
        int f4 = ii * 256 + t;
        int rr = f4 >> 6, c = (f4 & 63) * 4;
        int r = rt * 16 + rr;
        int h = r >> 7, n = r & 127;
        float4 xv = *(const float4*)(memory_w + n * 2048 + h * 256 + c);
        ushort hh[4], ll[4];
        split_bf16(xv.x, hh[0], ll[0]); split_bf16(xv.y, hh[1], ll[1]);
        split_bf16(xv.z, hh[2], ll[2]); split_bf16(xv.w, hh[3], ll[3]);
        uint2 ph = { (uint)hh[0] | ((uint)hh[1] << 16), (uint)hh[2] | ((uint)hh[3] << 16) };
        uint2 pl = { (uint)ll[0] | ((uint)ll[1] << 16), (uint)ll[2] | ((uint)ll[3] << 16) };
        *(uint2*)(xhi + rr * 264 + c) = ph;
        *(uint2*)(xlo + rr * 264 + c) = pl;
    }
    __syncthreads();
    int l = t & 63, w = t >> 6;
    int lr = l & 15, quad = l >> 4;
    int tg = cq * 4 + w;
    const uint4* H4 = (const uint4*)(Whi + (6 + msel) * 65536);
    const uint4* L4 = (const uint4*)(Wlo + (6 + msel) * 65536);
    const ushort* ah = xhi + lr * 264 + quad * 8;
    const ushort* al = xlo + lr * 264 + quad * 8;
    f32x4 acc = {};
    #pragma unroll 4
    for (int ks = 0; ks < 8; ++ks) {
        short8 a_h = lds_frag(ah + ks * 32);
        short8 a_l = lds_frag(al + ks * 32);
        int off = (tg * 8 + ks) * 64 + l;
        V8 bh, bl; bh.u = H4[off]; bl.u = L4[off];
        acc = __builtin_amdgcn_mfma_f32_16x16x32_bf16(a_h, bh.s, acc, 0, 0, 0);
        acc = __builtin_amdgcn_mfma_f32_16x16x32_bf16(a_l, bh.s, acc, 0, 0, 0);
        acc = __builtin_amdgcn_mfma_f32_16x16x32_bf16(a_h, bl.s, acc, 0, 0, 0);
    }
    float* O = msel ? Bm : A;
    int n0 = tg * 16 + lr;
    #pragma unroll
    for (int r = 0; r < 4; ++r)
        O[(rt * 16 + quad * 4 + r) * 256 + n0] = acc[r];
}

// ---------------------------------------------------------------------------
// conn v2 (LDS-tiled): maskb[h,i,j] = bf16( conn ? 0 : -1e9 ).
// grid 512 = h(8) x itile(8) x jtile(8); 256 thr = (il 0..15) x (jl 0..15).
// A rows (j) and B rows (i, +fc_out_b) staged coalesced into LDS.
// ---------------------------------------------------------------------------
__global__ __launch_bounds__(256) void k_conn(
    const float* __restrict__ A, const float* __restrict__ Bm,
    const float* __restrict__ fc_out_b, const float* __restrict__ fc_cat_w,
    const float* __restrict__ fc_cat_b, const float* __restrict__ gumbel_u,
    ushort* __restrict__ maskb) {
    int bx = blockIdx.x;
    int h = bx >> 6, it = (bx >> 3) & 7, jt = bx & 7;
    int i0 = it * 16, j0 = jt * 16;
    int t = threadIdx.x;
    int il = t >> 4, jl = t & 15;
    __shared__ __align__(16) float sA[16 * 260], sB[16 * 260];
    #pragma unroll
    for (int p = 0; p < 4; ++p) {
        int idx = p * 256 + t;
        int rr = idx >> 6, c = (idx & 63) * 4;
        *(float4*)(sA + rr * 260 + c) =
            *(const float4*)(A + (h * 128 + j0 + rr) * 256 + c);
        float4 bv = *(const float4*)(Bm + (h * 128 + i0 + rr) * 256 + c);
        float4 fb = *(const float4*)(fc_out_b + c);
        bv.x += fb.x; bv.y += fb.y; bv.z += fb.z; bv.w += fb.w;
        *(float4*)(sB + rr * 260 + c) = bv;
    }
    __syncthreads();
    const float* Ar = sA + jl * 260;
    const float* Br = sB + il * 260;
    float l0 = fc_cat_b[0], l1 = fc_cat_b[1];
    #pragma unroll 4
    for (int d4 = 0; d4 < 64; ++d4) {
        int d = d4 * 4;
        float4 av = *(const float4*)(Ar + d);
        float4 bv = *(const float4*)(Br + d);
        float4 cwA = *(const float4*)(fc_cat_w + d * 2);      // w0[d],w1[d],w0[d+1],w1[d+1]
        float4 cwB = *(const float4*)(fc_cat_w + d * 2 + 4);
        float h0 = fmaxf(av.x + bv.x, 0.f);
        float h1 = fmaxf(av.y + bv.y, 0.f);
        float h2 = fmaxf(av.z + bv.z, 0.f);
        float h3 = fmaxf(av.w + bv.w, 0.f);
        l0 += h0 * cwA.x + h1 * cwA.z + h2 * cwB.x + h3 * cwB.z;
        l1 += h0 * cwA.y + h1 * cwA.w + h2 * cwB.y + h3 * cwB.w;
    }
    int i = i0 + il, j = j0 + jl;
    float2 uu = *(const float2*)(gumbel_u + ((h * 128 + i) * 128 + j) * 2);
    float g0 = -logf(-logf(uu.x + 1e-10f) + 1e-10f);
    float g1 = -logf(-logf(uu.y + 1e-10f) + 1e-10f);
    bool on = (l1 + g1) > (l0 + g0);
    maskb[(h * 128 + i) * 128 + j] = bf16bits(on ? 0.f : -1e9f);
}

// ---------------------------------------------------------------------------
// MFMA GEMM: Y[4096,256] = act(X @ W + b). grid (256 rowtiles, 4 colquads),
// 256 thr = 4 waves; wave w -> single coltile tg = cq*4 + w.
// ---------------------------------------------------------------------------
template <int ACT>
__global__ __launch_bounds__(256) void k_gemm16(
    const float* __restrict__ X, const ushort* __restrict__ Whi,
    const ushort* __restrict__ Wlo, const float* __restrict__ bias,
    float* __restrict__ Y) {
    __shared__ __align__(16) ushort xhi[16 * 264], xlo[16 * 264];
    int t = threadIdx.x;
    int r0 = blockIdx.x * 16;
    #pragma unroll
    for (int ii = 0; ii < 4; ++ii) {
        int f4 = ii * 256 + t;
        int row = f4 >> 6, c = (f4 & 63) * 4;
        float4 xv = *(const float4*)(X + (r0 + row) * 256 + c);
        ushort h[4], l[4];
        split_bf16(xv.x, h[0], l[0]); split_bf16(xv.y, h[1], l[1]);
        split_bf16(xv.z, h[2], l[2]); split_bf16(xv.w, h[3], l[3]);
        uint2 ph = { (uint)h[0] | ((uint)h[1] << 16), (uint)h[2] | ((uint)h[3] << 16) };
        uint2 pl = { (uint)l[0] | ((uint)l[1] << 16), (uint)l[2] | ((uint)l[3] << 16) };
        *(uint2*)(xhi + row * 264 + c) = ph;
        *(uint2*)(xlo + row * 264 + c) = pl;
    }
    __syncthreads();
    int l = t & 63, w = t >> 6;
    int lr = l & 15, quad = l >> 4;
    int tg = blockIdx.y * 4 + w;
    const ushort* ah = xhi + lr * 264 + quad * 8;
    const ushort* al = xlo + lr * 264 + quad * 8;
    const uint4* H4 = (const uint4*)Whi;
    const uint4* L4 = (const uint4*)Wlo;
    f32x4 acc = {};
    #pragma unroll 4
    for (int ks = 0; ks < 8; ++ks) {
        short8 a_h = lds_frag(ah + ks * 32);
        short8 a_l = lds_frag(al + ks * 32);
        int off = (tg * 8 + ks) * 64 + l;
        V8 bh, bl; bh.u = H4[off]; bl.u = L4[off];
        acc = __builtin_amdgcn_mfma_f32_16x16x32_bf16(a_h, bh.s, acc, 0, 0, 0);
        acc = __builtin_amdgcn_mfma_f32_16x16x32_bf16(a_l, bh.s, acc, 0, 0, 0);
        acc = __builtin_amdgcn_mfma_f32_16x16x32_bf16(a_h, bl.s, acc, 0, 0, 0);
    }
    int n0 = tg * 16 + lr;
    float bs = bias[n0];
    #pragma unroll
    for (int r = 0; r < 4; ++r) {
        float o = acc[r] + bs;
        if (ACT) o = gelu_f(o);
        Y[(r0 + quad * 4 + r) * 256 + n0] = o;
    }
}

// ---------------------------------------------------------------------------
// qkv: grid (256 rowtiles, 12): osel = y>>2 (0=Q 1=K 2=V), cq = y&3.
// ---------------------------------------------------------------------------
__global__ __launch_bounds__(256) void k_qkv(
    const float* __restrict__ X, const ushort* __restrict__ Whi,
    const ushort* __restrict__ Wlo,
    const float* __restrict__ Bq, const float* __restrict__ Bk,
    const float* __restrict__ Bv,
    float* __restrict__ Q, float* __restrict__ K, float* __restrict__ V) {
    __shared__ __align__(16) ushort xhi[16 * 264], xlo[16 * 264];
    int t = threadIdx.x;
    int r0 = blockIdx.x * 16;
    int osel = blockIdx.y >> 2, cq = blockIdx.y & 3;
    #pragma unroll
    for (int ii = 0; ii < 4; ++ii) {
        int f4 = ii * 256 + t;
        int row = f4 >> 6, c = (f4 & 63) * 4;
        float4 xv = *(const float4*)(X + (r0 + row) * 256 + c);
        ushort h[4], l[4];
        split_bf16(xv.x, h[0], l[0]); split_bf16(xv.y, h[1], l[1]);
        split_bf16(xv.z, h[2], l[2]); split_bf16(xv.w, h[3], l[3]);
        uint2 ph = { (uint)h[0] | ((uint)h[1] << 16), (uint)h[2] | ((uint)h[3] << 16) };
        uint2 pl = { (uint)l[0] | ((uint)l[1] << 16), (uint)l[2] | ((uint)l[3] << 16) };
        *(uint2*)(xhi + row * 264 + c) = ph;
        *(uint2*)(xlo + row * 264 + c) = pl;
    }
    __syncthreads();
    int l = t & 63, w = t >> 6;
    int lr = l & 15, quad = l >> 4;
    int tg = cq * 4 + w;
    const ushort* ah = xhi + lr * 264 + quad * 8;
    const ushort* al = xlo + lr * 264 + quad * 8;
    const uint4* H4 = (const uint4*)(Whi + (2 + osel) * 65536);
    const uint4* L4 = (const uint4*)(Wlo + (2 + osel) * 65536);
    f32x4 acc = {};
    #pragma unroll 4
    for (int ks = 0; ks < 8; ++ks) {
        short8 a_h = lds_frag(ah + ks * 32);
        short8 a_l = lds_frag(al + ks * 32);
        int off = (tg * 8 + ks) * 64 + l;
        V8 bh, bl; bh.u = H4[off]; bl.u = L4[off];
        acc = __builtin_amdgcn_mfma_f32_16x16x32_bf16(a_h, bh.s, acc, 0, 0, 0);
        acc = __builtin_amdgcn_mfma_f32_16x16x32_bf16(a_l, bh.s, acc, 0, 0, 0);
        acc = __builtin_amdgcn_mfma_f32_16x16x32_bf16(a_h, bl.s, acc, 0, 0, 0);
    }
    const float* Bp = osel == 0 ? Bq : osel == 1 ? Bk : Bv;
    float* O = osel == 0 ? Q : osel == 1 ? K : V;
    int n0 = tg * 16 + lr;
    float bs = Bp[n0];
    #pragma unroll
    for (int r = 0; r < 4; ++r)
        O[(r0 + quad * 4 + r) * 256 + n0] = acc[r] + bs;
}

// ---------------------------------------------------------------------------
// MFMA attention: grid 512 = (b, h, rowhalf); 256 thr = 4 waves;
// wave w -> row tile rt = rh*4 + w (16 q-rows). Mask read from global bf16.
// ---------------------------------------------------------------------------
__global__ __launch_bounds__(256) void k_attn_mfma(
    const float* __restrict__ Q, const float* __restrict__ K,
    const float* __restrict__ V, const ushort* __restrict__ maskb,
    float* __restrict__ AO) {
    int bx = blockIdx.x;
    int b = bx >> 4, h = (bx >> 1) & 7, rh = bx & 1;
    int t = threadIdx.x;
    int lane = t & 63, w = t >> 6;
    __shared__ __align__(16) ushort vT[32 * 136];
    __shared__ __align__(16) ushort ps[64 * 136];
    #pragma unroll
    for (int it = 0; it < 4; ++it) {
        int f4 = it * 256 + t;
        int key = f4 >> 3, dq = (f4 & 7) * 4;
        float4 vv = *(const float4*)(V + b * 32768 + key * 256 + h * 32 + dq);
        vT[(dq + 0) * 136 + key] = bf16bits(vv.x);
        vT[(dq + 1) * 136 + key] = bf16bits(vv.y);
        vT[(dq + 2) * 136 + key] = bf16bits(vv.z);
        vT[(dq + 3) * 136 + key] = bf16bits(vv.w);
    }
    __syncthreads();
    int lr = lane & 15, quad = lane >> 4;
    int rt = rh * 4 + w;
    // QK^T
    const float* qp = Q + b * 32768 + (rt * 16 + lr) * 256 + h * 32 + quad * 8;
    float4 q0 = *(const float4*)qp, q1 = *(const float4*)(qp + 4);
    V8 af;
    af.u.x = pk(q0.x, q0.y); af.u.y = pk(q0.z, q0.w);
    af.u.z = pk(q1.x, q1.y); af.u.w = pk(q1.z, q1.w);
    f32x4 s[8];
    #pragma unroll
    for (int ct = 0; ct < 8; ++ct) {
        const float* kp = K + b * 32768 + (ct * 16 + lr) * 256 + h * 32 + quad * 8;
        float4 k0 = *(const float4*)kp, k1 = *(const float4*)(kp + 4);
        V8 bf_;
        bf_.u.x = pk(k0.x, k0.y); bf_.u.y = pk(k0.z, k0.w);
        bf_.u.z = pk(k1.x, k1.y); bf_.u.w = pk(k1.z, k1.w);
        f32x4 z = {0.f, 0.f, 0.f, 0.f};
        s[ct] = __builtin_amdgcn_mfma_f32_16x16x32_bf16(af.s, bf_.s, z, 0, 0, 0);
    }
    const float scale = 0.17677669529663687f;  // 32^-0.5
    const ushort* mrow = maskb + h * 16384;
    #pragma unroll
    for (int r = 0; r < 4; ++r) {
        int lrow = w * 16 + quad * 4 + r;
        int grow = rt * 16 + quad * 4 + r;
        float sv[8];
        float mx = -3.0e38f;
        #pragma unroll
        for (int ct = 0; ct < 8; ++ct) {
            float bias = bits_to_f(mrow[grow * 128 + ct * 16 + lr]);
            sv[ct] = s[ct][r] * scale + bias;
            mx = fmaxf(mx, sv[ct]);
        }
        mx = fmaxf(mx, __shfl_xor(mx, 1));
        mx = fmaxf(mx, __shfl_xor(mx, 2));
        mx = fmaxf(mx, __shfl_xor(mx, 4));
        mx = fmaxf(mx, __shfl_xor(mx, 8));
        float sum = 0.f;
        #pragma unroll
        for (int ct = 0; ct < 8; ++ct) {
            sv[ct] = __expf(sv[ct] - mx);
            sum += sv[ct];
        }
        sum += __shfl_xor(sum, 1);
        sum += __shfl_xor(sum, 2);
        sum += __shfl_xor(sum, 4);
        sum += __shfl_xor(sum, 8);
        float iv = 1.f / sum;
        #pragma unroll
        for (int ct = 0; ct < 8; ++ct)
            ps[lrow * 136 + ct * 16 + lr] = bf16bits(sv[ct] * iv);
    }
    // PV (rows wave-private)
    f32x4 o0 = {}, o1 = {};
    #pragma unroll
    for (int kk = 0; kk < 4; ++kk) {
        short8 pa = lds_frag(ps + (w * 16 + lr) * 136 + kk * 32 + quad * 8);
        short8 v0 = lds_frag(vT + lr * 136 + kk * 32 + quad * 8);
        short8 v1 = lds_frag(vT + (16 + lr) * 136 + kk * 32 + quad * 8);
        o0 = __builtin_amdgcn_mfma_f32_16x16x32_bf16(pa, v0, o0, 0, 0, 0);
        o1 = __builtin_amdgcn_mfma_f32_16x16x32_bf16(pa, v1, o1, 0, 0, 0);
    }
    #pragma unroll
    for (int r = 0; r < 4; ++r) {
        int grow = rt * 16 + quad * 4 + r;
        float* op = AO + b * 32768 + grow * 256 + h * 32;
        op[lr] = o0[r];
        op[16 + lr] = o1[r];
    }
}

// ---------------------------------------------------------------------------
extern "C" void kernel_launch(void* const* d_in, const int* in_sizes, int n_in,
                              void* d_out, int out_size, void* d_ws, size_t ws_size,
                              hipStream_t stream) {
    const float* x        = (const float*)d_in[0];
    const float* gumbel_u = (const float*)d_in[1];
    const float* memory_w = (const float*)d_in[2];
    const float* fc_out_w = (const float*)d_in[3];
    const float* fc_out_b = (const float*)d_in[4];
    const float* fc_cat_w = (const float*)d_in[5];
    const float* fc_cat_b = (const float*)d_in[6];
    const float* wq       = (const float*)d_in[7];
    const float* bq       = (const float*)d_in[8];
    const float* wk       = (const float*)d_in[9];
    const float* bk       = (const float*)d_in[10];
    const float* wv_      = (const float*)d_in[11];
    const float* bv_      = (const float*)d_in[12];
    const float* out_w    = (const float*)d_in[13];
    const float* out_b    = (const float*)d_in[14];
    const float* mlp_w1   = (const float*)d_in[15];
    const float* mlp_b1   = (const float*)d_in[16];
    const float* mlp_w2   = (const float*)d_in[17];
    const float* mlp_b2   = (const float*)d_in[18];

    float* ws    = (float*)d_ws;
    float* A     = ws;                  //  262144 f
    float* Bm    = ws + 262144;         //  262144 f
    ushort* mask = (ushort*)(ws + 524288);   // 131072 ushort
    float* hbuf  = ws + 589824;         // 1048576 f
    float* xm    = ws + 1638400;        // 1048576 f
    float* q     = ws + 2686976;        // 1048576 f
    float* k     = ws + 3735552;        // 1048576 f
    float* v     = ws + 4784128;        // 1048576 f
    float* ao    = ws + 5832704;        // 1048576 f
    ushort* wf_hi = (ushort*)(ws + 6881280);  // 8*65536 ushort
    ushort* wf_lo = wf_hi + 8 * 65536;
    float* out   = (float*)d_out;

    // weight order: 0=mlp_w1 1=mlp_w2 2=wq 3=wk 4=wv 5=out_w 6,7=fc_out halves
    k_wprep<<<dim3(128), dim3(256), 0, stream>>>(
        mlp_w1, mlp_w2, wq, wk, wv_, out_w, fc_out_w, fc_out_w + 65536,
        wf_hi, wf_lo);
    k_featproj<<<dim3(64, 8), dim3(256), 0, stream>>>(memory_w, wf_hi, wf_lo, A, Bm);
    k_conn<<<dim3(512), dim3(256), 0, stream>>>(A, Bm, fc_out_b, fc_cat_w, fc_cat_b,
                                                gumbel_u, mask);
    k_gemm16<1><<<dim3(256, 4), dim3(256), 0, stream>>>(x, wf_hi + 0 * 65536,
                                                        wf_lo + 0 * 65536, mlp_b1, hbuf);
    k_gemm16<0><<<dim3(256, 4), dim3(256), 0, stream>>>(hbuf, wf_hi + 1 * 65536,
                                                        wf_lo + 1 * 65536, mlp_b2, xm);
    k_qkv<<<dim3(256, 12), dim3(256), 0, stream>>>(xm, wf_hi, wf_lo, bq, bk, bv_, q, k, v);
    k_attn_mfma<<<dim3(512), dim3(256), 0, stream>>>(q, k, v, mask, ao);
    k_gemm16<0><<<dim3(256, 4), dim3(256), 0, stream>>>(ao, wf_hi + 5 * 65536,
                                                        wf_lo + 5 * 65536, out_b, out);
}